// Round 1
// baseline (658.819 us; speedup 1.0000x reference)
//
#include <hip/hip_runtime.h>
#include <hip/hip_cooperative_groups.h>

// RainbowEvolution T=1024 L=32 D=512 P=512 H=2048. fp32 in / fp32 out.
// R7: single cooperative mega-kernel (was 19 launches). 256 blocks x 512 thr,
// 11 grid.sync()s. No atomics / no zero pass (all GEMMs full-K per block,
// MLP2 uses 4-way intra-block K split + LDS reduce). Phase 1 overlaps the
// query/task GEMM (33 blocks) with the 64MB base->SB scan (223 blocks).
// Tail (logits+softmax+EP+evo GEMM+LN_in) fused into one per-l-block phase.
// Scratch lives in d_out's aligned_prompts region; bcast (last phase)
// overwrites it after all reads complete.

namespace cg = cooperative_groups;

static constexpr int T_ = 1024, L_ = 32, D_ = 512, P_ = 512, H_ = 2048;
static constexpr float SCALE = 0.04419417382415922f; // 1/sqrt(512)
static constexpr float EPS_ = 1e-5f;
static constexpr int NB = 256;   // co-resident blocks (1 per CU guaranteed)
static constexpr int NT = 512;

// out layout (fp32 offsets): aligned, aligned_prompts, task_weights, feature_attn
static constexpr int OFFO_AL = 0;
static constexpr int OFFO_AP = 16384;
static constexpr int OFFO_TW = 16384 + 16777216;   // 16793600
static constexpr int OFFO_FA = OFFO_TW + 1024;     // 16794624

// scratch (fp32 offsets into ws = out + OFFO_AP)
static constexpr int OFF_SB      = 0;        // [1024][512] sum_l base
static constexpr int OFF_AQ      = 524288;   // [33][512] pre-bias query|tv
static constexpr int OFF_QUERY   = 541184;   // [32][512]
static constexpr int OFF_TV      = 557568;   // [512]
static constexpr int OFF_PQ      = 558080;   // [512]
static constexpr int OFF_WKTV    = 558592;   // [512]
static constexpr int OFF_WKPQ    = 559104;   // [512]
static constexpr int OFF_U       = 559616;   // [1024]
static constexpr int OFF_V       = 560640;   // [1024]
static constexpr int OFF_C       = 561664;   // [1024]
static constexpr int OFF_SC      = 562688;   // [64] scalars: bkt, bkq
static constexpr int OFF_PART    = 562752;   // [8][32][512]
static constexpr int OFF_WB      = 693824;   // [32][512]
static constexpr int OFF_AKV     = 710208;   // [2][32][512] pre-bias K|V
static constexpr int OFF_EVOLVED = 742976;   // [32][512]
static constexpr int OFF_AH1     = 759360;   // [32][2048] pre-bias pre-relu
static constexpr int OFF_AOUT    = 824896;   // [32][512]

// ---- reductions (512-thread block) ----
__device__ __forceinline__ float wred64(float v) {
    #pragma unroll
    for (int off = 32; off > 0; off >>= 1) v += __shfl_down(v, off, 64);
    return v;
}
__device__ __forceinline__ float wmax64(float v) {
    #pragma unroll
    for (int off = 32; off > 0; off >>= 1) v = fmaxf(v, __shfl_down(v, off, 64));
    return v;
}
__device__ __forceinline__ float bsum(float v, float* buf, int tid) {
    v = wred64(v);
    if ((tid & 63) == 0) buf[tid >> 6] = v;
    __syncthreads();
    if (tid == 0) {
        float s = 0.f;
        #pragma unroll
        for (int i = 0; i < 8; ++i) s += buf[i];
        buf[0] = s;
    }
    __syncthreads();
    float r = buf[0];
    __syncthreads();
    return r;
}
__device__ __forceinline__ float bmax(float v, float* buf, int tid) {
    v = wmax64(v);
    if ((tid & 63) == 0) buf[tid >> 6] = v;
    __syncthreads();
    if (tid == 0) {
        float s = buf[0];
        #pragma unroll
        for (int i = 1; i < 8; ++i) s = fmaxf(s, buf[i]);
        buf[0] = s;
    }
    __syncthreads();
    float r = buf[0];
    __syncthreads();
    return r;
}

__global__ __launch_bounds__(512, 2) void mega(
    const float* __restrict__ base, const float* __restrict__ np_,
    const float* __restrict__ te,   const float* __restrict__ Wq,
    const float* __restrict__ Wt,   const float* __restrict__ bq,
    const float* __restrict__ bt,   const float* __restrict__ Wk,
    const float* __restrict__ bk,   const float* __restrict__ Wv,
    const float* __restrict__ bv,   const float* __restrict__ Wo,
    const float* __restrict__ bo,   const float* __restrict__ Wa1,
    const float* __restrict__ ba1,  const float* __restrict__ Wa2,
    const float* __restrict__ ba2,  const float* __restrict__ g_in,
    const float* __restrict__ b_in, const float* __restrict__ g_out,
    const float* __restrict__ b_out, float* __restrict__ out)
{
    cg::grid_group grid = cg::this_grid();
    __shared__ __align__(16) float smem[2560];   // 10.25 KB
    float* ws = out + OFFO_AP;
    const int blk = blockIdx.x, tid = threadIdx.x;

    // ---- P1: AQ = (np|te) @ (Wq|Wt) full-K (blocks 0..32)
    //          SB[t,d] = sum_l base[t,l,d]   (blocks 33..255)
    if (blk < 33) {
        const float* x = (blk < 32) ? (np_ + blk * D_) : te;
        const float* W = (blk < 32) ? Wq : Wt;
        smem[tid] = x[tid];
        __syncthreads();
        float acc = 0.f;
        #pragma unroll 8
        for (int j = 0; j < D_; ++j) acc = fmaf(smem[j], W[j * P_ + tid], acc);
        ws[OFF_AQ + blk * P_ + tid] = acc;
    } else {
        for (int t = blk - 33; t < T_; t += NB - 33) {
            const float* bp = base + (size_t)t * (L_ * D_);
            float s = 0.f;
            #pragma unroll
            for (int l = 0; l < L_; ++l) s += bp[l * D_ + tid];
            ws[OFF_SB + t * D_ + tid] = s;
        }
    }
    grid.sync();

    // ---- P2: QUERY = AQ+bq ; TV = tanh(AQ[32]+bt) ; PQ = meanAQ + bq
    if (blk < 32) {
        ws[OFF_QUERY + blk * P_ + tid] = ws[OFF_AQ + blk * P_ + tid] + bq[tid];
    } else if (blk == 32) {
        ws[OFF_TV + tid] = tanhf(ws[OFF_AQ + 32 * P_ + tid] + bt[tid]);
    } else if (blk == 33) {
        float s = 0.f;
        #pragma unroll
        for (int l = 0; l < L_; ++l) s += ws[OFF_AQ + l * P_ + tid];
        ws[OFF_PQ + tid] = s * (1.f / L_) + bq[tid];
    }
    grid.sync();

    // ---- P3: WKTV[d]=Wk[d,:]·TV, WKPQ[d]=Wk[d,:]·PQ (blocks 0..63, wave/d)
    //          bkt=bk·TV, bkq=bk·PQ (block 64)
    if (blk < 64) {
        int wv = tid >> 6, lane = tid & 63;
        int d = blk * 8 + wv;
        const float4* row = (const float4*)(Wk + d * P_);
        const float4* tv4 = (const float4*)(ws + OFF_TV);
        const float4* pq4 = (const float4*)(ws + OFF_PQ);
        float4 a = row[lane * 2], b = row[lane * 2 + 1];
        float4 t0 = tv4[lane * 2], t1 = tv4[lane * 2 + 1];
        float4 q0 = pq4[lane * 2], q1 = pq4[lane * 2 + 1];
        float pa = a.x * t0.x + a.y * t0.y + a.z * t0.z + a.w * t0.w
                 + b.x * t1.x + b.y * t1.y + b.z * t1.z + b.w * t1.w;
        float pb = a.x * q0.x + a.y * q0.y + a.z * q0.z + a.w * q0.w
                 + b.x * q1.x + b.y * q1.y + b.z * q1.z + b.w * q1.w;
        pa = wred64(pa); pb = wred64(pb);
        if (lane == 0) { ws[OFF_WKTV + d] = pa; ws[OFF_WKPQ + d] = pb; }
    } else if (blk == 64) {
        float pbt = bk[tid] * ws[OFF_TV + tid];
        float pbq = bk[tid] * ws[OFF_PQ + tid];
        pbt = bsum(pbt, smem, tid);
        pbq = bsum(pbq, smem, tid);
        if (tid == 0) { ws[OFF_SC] = pbt; ws[OFF_SC + 1] = pbq; }
    }
    grid.sync();

    // ---- P4: U[t] = (SB[t]·WKTV)/L ; V[t] = (SB[t]·WKPQ)/L  (4 t per block)
    for (int t = blk; t < T_; t += NB) {
        float sb = ws[OFF_SB + t * D_ + tid];
        float a = bsum(sb * ws[OFF_WKTV + tid], smem, tid);
        float b = bsum(sb * ws[OFF_WKPQ + tid], smem, tid);
        if (tid == 0) {
            ws[OFF_U + t] = a * (1.f / L_);
            ws[OFF_V + t] = b * (1.f / L_);
        }
    }
    grid.sync();

    // ---- P5: softmax chain -> task_weights, C  (block 0, 2 t per thread)
    if (blk == 0) {
        float* buf = smem;
        float bkt = ws[OFF_SC], bkq = ws[OFF_SC + 1];
        float s1[2], e1[2], tw1[2];
        float lmax = -1e30f;
        #pragma unroll
        for (int k = 0; k < 2; ++k) {
            s1[k] = (ws[OFF_U + tid + k * NT] + bkt) * SCALE;
            lmax = fmaxf(lmax, s1[k]);
        }
        float gmax = bmax(lmax, buf, tid);
        float ls = 0.f;
        #pragma unroll
        for (int k = 0; k < 2; ++k) { e1[k] = expf(s1[k] - gmax); ls += e1[k]; }
        float gs = bsum(ls, buf, tid);
        #pragma unroll
        for (int k = 0; k < 2; ++k) tw1[k] = e1[k] / gs;

        float p2[2], e2[2];
        lmax = -1e30f;
        #pragma unroll
        for (int k = 0; k < 2; ++k) {
            p2[k] = ((1.f + tw1[k]) * ws[OFF_V + tid + k * NT] + bkq) * SCALE;
            lmax = fmaxf(lmax, p2[k]);
        }
        gmax = bmax(lmax, buf, tid);
        ls = 0.f;
        #pragma unroll
        for (int k = 0; k < 2; ++k) { e2[k] = expf(p2[k] - gmax); ls += e2[k]; }
        gs = bsum(ls, buf, tid);

        float tw[2], lsum = 0.f;
        #pragma unroll
        for (int k = 0; k < 2; ++k) {
            tw[k] = 0.5f * tw1[k] + 0.5f * (e2[k] / gs);
            lsum += tw[k];
        }
        float S = bsum(lsum, buf, tid);
        S = fmaxf(S, 1e-6f);
        #pragma unroll
        for (int k = 0; k < 2; ++k) {
            int t = tid + k * NT;
            float twn = tw[k] / S;
            out[OFFO_TW + t] = twn;
            ws[OFF_C + t] = twn * (1.f + tw1[k]);
        }
    }
    grid.sync();

    // ---- P6: PART[ch,l,:] = sum_{t in chunk} C_t * base[t,l,:]  (all 256 blocks)
    {
        int l = blk & 31, ch = blk >> 5;           // ch 0..7, 128 t each
        int d4 = tid & 127, tq = tid >> 7;         // 4-way t split
        float* sc = smem + 2048;
        if (tid < 128) sc[tid] = ws[OFF_C + ch * 128 + tid];
        __syncthreads();
        float4 acc = make_float4(0.f, 0.f, 0.f, 0.f);
        for (int i = tq; i < 128; i += 4) {
            int t = ch * 128 + i;
            float c = sc[i];
            float4 v = ((const float4*)(base + ((size_t)t * L_ + l) * D_))[d4];
            acc.x = fmaf(c, v.x, acc.x);
            acc.y = fmaf(c, v.y, acc.y);
            acc.z = fmaf(c, v.z, acc.z);
            acc.w = fmaf(c, v.w, acc.w);
        }
        float4* s4 = (float4*)smem;
        s4[tid] = acc;
        __syncthreads();
        if (tid < 128) {
            float4 a = s4[tid], b = s4[tid + 128], c2 = s4[tid + 256], d2 = s4[tid + 384];
            float4 r;
            r.x = a.x + b.x + c2.x + d2.x;
            r.y = a.y + b.y + c2.y + d2.y;
            r.z = a.z + b.z + c2.z + d2.z;
            r.w = a.w + b.w + c2.w + d2.w;
            ((float4*)(ws + OFF_PART + (ch * 32 + l) * D_))[tid] = r;
        }
    }
    grid.sync();

    // ---- P7: WB[l] = sum_ch PART ; AKV[sel,l] = WB[l] @ (Wk|Wv) full-K (64 blocks)
    if (blk < 64) {
        int l = blk >> 1, sel = blk & 1;
        float s = 0.f;
        #pragma unroll
        for (int ch = 0; ch < 8; ++ch) s += ws[OFF_PART + (ch * 32 + l) * D_ + tid];
        smem[tid] = s;
        if (sel == 0) ws[OFF_WB + l * D_ + tid] = s;
        __syncthreads();
        const float* W = sel ? Wv : Wk;
        float acc = 0.f;
        #pragma unroll 8
        for (int j = 0; j < D_; ++j) acc = fmaf(smem[j], W[j * P_ + tid], acc);
        ws[OFF_AKV + (sel * L_ + l) * P_ + tid] = acc;   // pre-bias
    }
    grid.sync();

    // ---- P8: per-l fused tail: logits+softmax -> FA ; EP ; EP@Wo ; LN_in (32 blocks)
    if (blk < 32) {
        int l = blk;
        float* sq  = smem;          // 512
        float* slg = smem + 512;    // 32
        float* sfa = smem + 544;    // 32
        float* sep = smem + 576;    // 512
        float* buf = smem + 1088;   // 8
        sq[tid] = ws[OFF_QUERY + l * P_ + tid];
        __syncthreads();
        int wv = tid >> 6, lane = tid & 63;
        const float4* sq4 = (const float4*)sq;
        const float4* bk4 = (const float4*)bk;
        float4 q0 = sq4[lane * 2], q1 = sq4[lane * 2 + 1];
        float4 kb0 = bk4[lane * 2], kb1 = bk4[lane * 2 + 1];
        #pragma unroll
        for (int gi = 0; gi < 4; ++gi) {
            int g = wv * 4 + gi;
            const float4* kr = (const float4*)(ws + OFF_AKV + g * P_);
            float4 a = kr[lane * 2], b = kr[lane * 2 + 1];
            float s = (a.x + kb0.x) * q0.x + (a.y + kb0.y) * q0.y
                    + (a.z + kb0.z) * q0.z + (a.w + kb0.w) * q0.w
                    + (b.x + kb1.x) * q1.x + (b.y + kb1.y) * q1.y
                    + (b.z + kb1.z) * q1.z + (b.w + kb1.w) * q1.w;
            s = wred64(s);
            if (lane == 0) slg[g] = s * SCALE;
        }
        __syncthreads();
        if (tid < 32) {
            float mx = -1e30f;
            for (int i = 0; i < 32; ++i) mx = fmaxf(mx, slg[i]);
            float S = 0.f;
            for (int i = 0; i < 32; ++i) S += expf(slg[i] - mx);
            float f = expf(slg[tid] - mx) / S;
            sfa[tid] = f;
            out[OFFO_FA + l * 32 + tid] = f;
        }
        __syncthreads();
        float bvp = bv[tid];
        float acc = 0.f;
        #pragma unroll 8
        for (int j = 0; j < L_; ++j)
            acc = fmaf(sfa[j], ws[OFF_AKV + (L_ + j) * P_ + tid] + bvp, acc);
        sep[tid] = acc;
        __syncthreads();
        float ev = 0.f;
        #pragma unroll 8
        for (int j = 0; j < D_; ++j) ev = fmaf(sep[j], Wo[j * D_ + tid], ev);
        float x = ws[OFF_WB + l * D_ + tid] + ev + bo[tid];
        float mean = bsum(x, buf, tid) * (1.f / D_);
        float dx = x - mean;
        float var = bsum(dx * dx, buf, tid) * (1.f / D_);
        ws[OFF_EVOLVED + l * D_ + tid] = dx * rsqrtf(var + EPS_) * g_in[tid] + b_in[tid];
    }
    grid.sync();

    // ---- P9: AH1[l,h] = EVOLVED[l] @ Wa1 full-K (128 blocks: l x hc)
    if (blk < 128) {
        int l = blk >> 2, hc = blk & 3;
        smem[tid] = ws[OFF_EVOLVED + l * D_ + tid];
        __syncthreads();
        int h = hc * 512 + tid;
        float acc = 0.f;
        #pragma unroll 8
        for (int j = 0; j < D_; ++j) acc = fmaf(smem[j], Wa1[j * H_ + h], acc);
        ws[OFF_AH1 + l * H_ + h] = acc;   // pre-bias pre-relu
    }
    grid.sync();

    // ---- P10: AOUT[l,d] = relu(AH1+ba1) @ Wa2, K=2048 via 4-way lane split
    //           (128 blocks: l x dq, 128 cols each)
    if (blk < 128) {
        int l = blk >> 2, dq = blk & 3;
        float* sx  = smem;           // 2048
        float* buf = smem + 2048;    // 512
        #pragma unroll
        for (int k = 0; k < 4; ++k) {
            int h = k * 512 + tid;
            sx[h] = fmaxf(ws[OFF_AH1 + l * H_ + h] + ba1[h], 0.f);
        }
        __syncthreads();
        int col = tid & 127, ks = tid >> 7;
        int d = dq * 128 + col;
        int j0 = ks * 512;
        float acc = 0.f;
        #pragma unroll 8
        for (int j = j0; j < j0 + 512; ++j) acc = fmaf(sx[j], Wa2[j * D_ + d], acc);
        buf[tid] = acc;
        __syncthreads();
        if (tid < 128) {
            float s = buf[tid] + buf[tid + 128] + buf[tid + 256] + buf[tid + 384];
            ws[OFF_AOUT + l * D_ + dq * 128 + tid] = s;
        }
    }
    grid.sync();

    // ---- P11: aligned = LN(EVOLVED + AOUT + ba2)*g_out + b_out (32 blocks)
    if (blk < 32) {
        int l = blk;
        float x = ws[OFF_EVOLVED + l * D_ + tid] + ws[OFF_AOUT + l * D_ + tid] + ba2[tid];
        float mean = bsum(x, smem, tid) * (1.f / D_);
        float dx = x - mean;
        float var = bsum(dx * dx, smem, tid) * (1.f / D_);
        out[OFFO_AL + l * D_ + tid] = dx * rsqrtf(var + EPS_) * g_out[tid] + b_out[tid];
    }
    grid.sync();

    // ---- P12: aligned_prompts = broadcast(aligned), 64 MB float4 write
    {
        const float4* src = (const float4*)out;        // 4096 float4
        float4* dst = (float4*)(out + OFFO_AP);
        int idx = blk * NT + tid;                      // 0..131071
        #pragma unroll
        for (int k = 0; k < 32; ++k) {
            int v = idx + k * (NB * NT);
            dst[v] = src[v & 4095];
        }
    }
}

extern "C" void kernel_launch(void* const* d_in, const int* in_sizes, int n_in,
                              void* d_out, int out_size, void* d_ws, size_t ws_size,
                              hipStream_t stream) {
    const float* base = (const float*)d_in[0];
    const float* np   = (const float*)d_in[1];
    const float* te   = (const float*)d_in[2];
    const float* Wt   = (const float*)d_in[3];
    const float* bt   = (const float*)d_in[4];
    const float* Wq   = (const float*)d_in[5];
    const float* bq   = (const float*)d_in[6];
    const float* Wk   = (const float*)d_in[7];
    const float* bk   = (const float*)d_in[8];
    const float* Wv   = (const float*)d_in[9];
    const float* bv   = (const float*)d_in[10];
    const float* Wo   = (const float*)d_in[11];
    const float* bo   = (const float*)d_in[12];
    const float* Wa1  = (const float*)d_in[13];
    const float* ba1  = (const float*)d_in[14];
    const float* Wa2  = (const float*)d_in[15];
    const float* ba2  = (const float*)d_in[16];
    const float* g_in = (const float*)d_in[17];
    const float* b_in = (const float*)d_in[18];
    const float* g_out= (const float*)d_in[19];
    const float* b_out= (const float*)d_in[20];
    float* out = (float*)d_out;

    void* args[] = {
        (void*)&base, (void*)&np, (void*)&te, (void*)&Wq, (void*)&Wt,
        (void*)&bq, (void*)&bt, (void*)&Wk, (void*)&bk, (void*)&Wv,
        (void*)&bv, (void*)&Wo, (void*)&bo, (void*)&Wa1, (void*)&ba1,
        (void*)&Wa2, (void*)&ba2, (void*)&g_in, (void*)&b_in, (void*)&g_out,
        (void*)&b_out, (void*)&out
    };
    hipLaunchCooperativeKernel((const void*)mega, dim3(NB), dim3(NT),
                               args, 0, stream);
}

// Round 3
// 295.825 us; speedup vs baseline: 2.2271x; 2.2271x over previous
//
#include <hip/hip_runtime.h>

// RainbowEvolution T=1024 L=32 D=512 P=512 H=2048. fp32 in / fp32 out.
// R8b: identical to R8 (container infra failure — never executed).
// 10 stream launches (was 19 in R0; cooperative mega-kernel R7 regressed:
// grid.sync() measured ~38us each). No atomics, no zero pass: all split-K
// GEMMs write partials summed by consumers. Base scan (64MB) overlapped with
// query GEMM in L1. Task softmax recomputed redundantly inside the weighted-
// pooling kernel (L4). Tail (logits+softmax+EP+evoGEMM+LN_in) fused per-l.
// Scratch in d_out's aligned_prompts region; bcast (last) overwrites it.

static constexpr int T_ = 1024, L_ = 32, D_ = 512, P_ = 512, H_ = 2048;
static constexpr float SCALE = 0.04419417382415922f; // 1/sqrt(512)
static constexpr float EPS_ = 1e-5f;

// out layout (fp32 offsets): aligned, aligned_prompts, task_weights, feature_attn
static constexpr int OFFO_AL = 0;
static constexpr int OFFO_AP = 16384;
static constexpr int OFFO_TW = 16384 + 16777216;   // 16793600
static constexpr int OFFO_FA = OFFO_TW + 1024;     // 16794624

// scratch (fp32 offsets into ws = out + OFFO_AP)
static constexpr int OFF_SB      = 0;        // [1024][512] sum_l base
static constexpr int OFF_AQP     = 524288;   // [4kc][33][512] query|tv partials
static constexpr int OFF_QUERY   = 591872;   // [32][512]
static constexpr int OFF_WKTV    = 608256;   // [512]
static constexpr int OFF_WKPQ    = 608768;   // [512]
static constexpr int OFF_SC      = 609280;   // [64] scalars: bkt, bkq
static constexpr int OFF_U       = 609344;   // [1024]
static constexpr int OFF_V       = 610368;   // [1024]
static constexpr int OFF_PART    = 611392;   // [32ch][32l][512]
static constexpr int OFF_WB      = 1135680;  // [32][512]
static constexpr int OFF_AKVP    = 1152064;  // [4kc][2sel][32][512]
static constexpr int OFF_EVOLVED = 1283136;  // [32][512]
static constexpr int OFF_AH1P    = 1299520;  // [4kc][32][2048]
static constexpr int OFF_AOUTP   = 1561664;  // [16kc][32][512]

// ---- reductions ----
__device__ __forceinline__ float wred64(float v) {
    #pragma unroll
    for (int off = 32; off > 0; off >>= 1) v += __shfl_down(v, off, 64);
    return v;
}
__device__ __forceinline__ float wmax64(float v) {
    #pragma unroll
    for (int off = 32; off > 0; off >>= 1) v = fmaxf(v, __shfl_down(v, off, 64));
    return v;
}
// 512-thread block sum (leading sync protects buf reuse)
__device__ __forceinline__ float bsum512(float v, float* buf, int tid) {
    v = wred64(v);
    __syncthreads();
    if ((tid & 63) == 0) buf[tid >> 6] = v;
    __syncthreads();
    float s = 0.f;
    #pragma unroll
    for (int i = 0; i < 8; ++i) s += buf[i];
    return s;
}
// 128-thread block sum/max
__device__ __forceinline__ float bsum128(float v, float* buf, int tid) {
    v = wred64(v);
    __syncthreads();
    if ((tid & 63) == 0) buf[tid >> 6] = v;
    __syncthreads();
    return buf[0] + buf[1];
}
__device__ __forceinline__ float bmax128(float v, float* buf, int tid) {
    v = wmax64(v);
    __syncthreads();
    if ((tid & 63) == 0) buf[tid >> 6] = v;
    __syncthreads();
    return fmaxf(buf[0], buf[1]);
}

// ---- L1: AQ partials GEMM (blocks 0..131) + SB scan (blocks 132..1155) ----
__global__ __launch_bounds__(512) void k_aq_sb(
    const float* __restrict__ base, const float* __restrict__ np_,
    const float* __restrict__ te, const float* __restrict__ Wq,
    const float* __restrict__ Wt, float* __restrict__ ws)
{
    __shared__ __align__(16) float4 smem4[512];   // 8 KB
    int blk = blockIdx.x, tid = threadIdx.x;
    if (blk < 132) {
        float* sx = (float*)smem4;                // 128 floats
        int b = blk % 33, kc = blk / 33;
        const float* x = (b < 32) ? (np_ + b * D_) : te;
        const float* W = (b < 32) ? Wq : Wt;
        if (tid < 128) sx[tid] = x[kc * 128 + tid];
        __syncthreads();
        float acc = 0.f;
        #pragma unroll 8
        for (int j = 0; j < 128; ++j) acc = fmaf(sx[j], W[(kc * 128 + j) * P_ + tid], acc);
        ws[OFF_AQP + (kc * 33 + b) * P_ + tid] = acc;
    } else {
        int t = blk - 132;
        const float4* bp = (const float4*)(base + (size_t)t * (L_ * D_));
        int d4 = tid & 127, lq = tid >> 7;
        float4 acc = make_float4(0.f, 0.f, 0.f, 0.f);
        #pragma unroll
        for (int i = 0; i < 8; ++i) {
            int l = i * 4 + lq;
            float4 v = bp[l * 128 + d4];
            acc.x += v.x; acc.y += v.y; acc.z += v.z; acc.w += v.w;
        }
        smem4[tid] = acc;
        __syncthreads();
        if (tid < 128) {
            float4 a = smem4[tid], b2 = smem4[tid + 128];
            float4 c = smem4[tid + 256], d2 = smem4[tid + 384];
            float4 r;
            r.x = a.x + b2.x + c.x + d2.x;
            r.y = a.y + b2.y + c.y + d2.y;
            r.z = a.z + b2.z + c.z + d2.z;
            r.w = a.w + b2.w + c.w + d2.w;
            ((float4*)(ws + OFF_SB + t * D_))[tid] = r;
        }
    }
}

// ---- L2: QUERY rows, TV/PQ (redundant), WKTV/WKPQ, bkt/bkq. grid 64 x 512 ----
__global__ __launch_bounds__(512) void k_prep(
    const float* __restrict__ Wk, const float* __restrict__ bk,
    const float* __restrict__ bq, const float* __restrict__ bt,
    float* __restrict__ ws)
{
    __shared__ __align__(16) float stv[512];
    __shared__ __align__(16) float spq[512];
    __shared__ float buf[8];
    int blk = blockIdx.x, tid = threadIdx.x;

    // TV (redundant per block): tanh(sum_kc AQP[kc][32] + bt)
    float a = 0.f;
    #pragma unroll
    for (int kc = 0; kc < 4; ++kc) a += ws[OFF_AQP + (kc * 33 + 32) * P_ + tid];
    stv[tid] = tanhf(a + bt[tid]);

    // PQ (redundant): mean_l (sum_kc AQP[kc][l]) + bq
    float b = 0.f;
    #pragma unroll 4
    for (int kc = 0; kc < 4; ++kc)
        for (int l = 0; l < 32; ++l) b += ws[OFF_AQP + (kc * 33 + l) * P_ + tid];
    spq[tid] = b * (1.f / 32.f) + bq[tid];

    // QUERY rows (blocks 0..31)
    if (blk < 32) {
        float q = bq[tid];
        #pragma unroll
        for (int kc = 0; kc < 4; ++kc) q += ws[OFF_AQP + (kc * 33 + blk) * P_ + tid];
        ws[OFF_QUERY + blk * P_ + tid] = q;
    }
    __syncthreads();

    // WKTV/WKPQ: wave per d (8 d's per block)
    int wv = tid >> 6, lane = tid & 63;
    int d = blk * 8 + wv;
    const float4* row = (const float4*)(Wk + d * P_);
    const float4* tv4 = (const float4*)stv;
    const float4* pq4 = (const float4*)spq;
    float4 r0 = row[lane * 2], r1 = row[lane * 2 + 1];
    float4 t0 = tv4[lane * 2], t1 = tv4[lane * 2 + 1];
    float4 q0 = pq4[lane * 2], q1 = pq4[lane * 2 + 1];
    float pa = r0.x * t0.x + r0.y * t0.y + r0.z * t0.z + r0.w * t0.w
             + r1.x * t1.x + r1.y * t1.y + r1.z * t1.z + r1.w * t1.w;
    float pb = r0.x * q0.x + r0.y * q0.y + r0.z * q0.z + r0.w * q0.w
             + r1.x * q1.x + r1.y * q1.y + r1.z * q1.z + r1.w * q1.w;
    pa = wred64(pa); pb = wred64(pb);
    if (lane == 0) { ws[OFF_WKTV + d] = pa; ws[OFF_WKPQ + d] = pb; }

    // bkt / bkq (block 63)
    if (blk == 63) {
        float bkf = bk[tid];
        float s1 = bsum512(bkf * stv[tid], buf, tid);
        float s2 = bsum512(bkf * spq[tid], buf, tid);
        if (tid == 0) { ws[OFF_SC] = s1; ws[OFF_SC + 1] = s2; }
    }
}

// ---- L3: U[t], V[t]. grid 1024 x 512 ----
__global__ __launch_bounds__(512) void k_uv(float* __restrict__ ws)
{
    __shared__ float buf[8];
    int t = blockIdx.x, tid = threadIdx.x;
    float sb = ws[OFF_SB + t * D_ + tid];
    float a = bsum512(sb * ws[OFF_WKTV + tid], buf, tid);
    float b = bsum512(sb * ws[OFF_WKPQ + tid], buf, tid);
    if (tid == 0) {
        ws[OFF_U + t] = a * (1.f / L_);
        ws[OFF_V + t] = b * (1.f / L_);
    }
}

// ---- L4: redundant task-softmax + weighted pooling PART. grid(32l,32ch) x128 ----
__global__ __launch_bounds__(128) void k_part(
    const float* __restrict__ base, float* __restrict__ out_tw,
    float* __restrict__ ws)
{
    __shared__ float sC[1024];
    __shared__ float rbuf[2];
    int l = blockIdx.x, ch = blockIdx.y, tid = threadIdx.x;
    float bkt = ws[OFF_SC], bkq = ws[OFF_SC + 1];

    float u[8], v[8], s1[8], tw1[8], tw[8];
    #pragma unroll
    for (int i = 0; i < 8; ++i) {
        int t = i * 128 + tid;
        u[i] = ws[OFF_U + t];
        v[i] = ws[OFF_V + t];
    }
    // softmax 1 -> tw1
    float lmax = -1e30f;
    #pragma unroll
    for (int i = 0; i < 8; ++i) { s1[i] = (u[i] + bkt) * SCALE; lmax = fmaxf(lmax, s1[i]); }
    float gmax = bmax128(lmax, rbuf, tid);
    float ls = 0.f;
    #pragma unroll
    for (int i = 0; i < 8; ++i) { s1[i] = expf(s1[i] - gmax); ls += s1[i]; }
    float gs = bsum128(ls, rbuf, tid);
    #pragma unroll
    for (int i = 0; i < 8; ++i) tw1[i] = s1[i] / gs;
    // softmax 2 (task_attn)
    lmax = -1e30f;
    #pragma unroll
    for (int i = 0; i < 8; ++i) {
        s1[i] = ((1.f + tw1[i]) * v[i] + bkq) * SCALE;
        lmax = fmaxf(lmax, s1[i]);
    }
    gmax = bmax128(lmax, rbuf, tid);
    ls = 0.f;
    #pragma unroll
    for (int i = 0; i < 8; ++i) { s1[i] = expf(s1[i] - gmax); ls += s1[i]; }
    gs = bsum128(ls, rbuf, tid);
    float lsum = 0.f;
    #pragma unroll
    for (int i = 0; i < 8; ++i) {
        tw[i] = 0.5f * tw1[i] + 0.5f * (s1[i] / gs);
        lsum += tw[i];
    }
    float S = bsum128(lsum, rbuf, tid);
    S = fmaxf(S, 1e-6f);
    #pragma unroll
    for (int i = 0; i < 8; ++i) {
        int t = i * 128 + tid;
        float twn = tw[i] / S;
        sC[t] = twn * (1.f + tw1[i]);
        if (l == 0 && ch == 0) out_tw[t] = twn;
    }
    __syncthreads();

    // PART[ch][l][:] = sum_{i<32} C[ch*32+i] * base[ch*32+i, l, :]
    float4 acc = make_float4(0.f, 0.f, 0.f, 0.f);
    for (int i = 0; i < 32; ++i) {
        int t = ch * 32 + i;
        float c = sC[t];
        float4 bv4 = ((const float4*)(base + ((size_t)t * L_ + l) * D_))[tid];
        acc.x = fmaf(c, bv4.x, acc.x);
        acc.y = fmaf(c, bv4.y, acc.y);
        acc.z = fmaf(c, bv4.z, acc.z);
        acc.w = fmaf(c, bv4.w, acc.w);
    }
    ((float4*)(ws + OFF_PART + (ch * 32 + l) * D_))[tid] = acc;
}

// ---- L5: WB reduce + split-K KV GEMM partials. grid 256 (l|sel|kc) x 512 ----
__global__ __launch_bounds__(512) void k_kv(
    const float* __restrict__ Wk, const float* __restrict__ Wv,
    float* __restrict__ ws)
{
    __shared__ float part[512];
    __shared__ float sx[128];
    int blk = blockIdx.x, tid = threadIdx.x;
    int l = blk & 31, sel = (blk >> 5) & 1, kc = blk >> 6;
    int p = tid & 127, c = tid >> 7;
    float s = 0.f;
    #pragma unroll
    for (int ch = c; ch < 32; ch += 4)
        s += ws[OFF_PART + (ch * 32 + l) * D_ + kc * 128 + p];
    part[tid] = s;
    __syncthreads();
    if (tid < 128) {
        float w = part[tid] + part[tid + 128] + part[tid + 256] + part[tid + 384];
        sx[tid] = w;
        if (sel == 0) ws[OFF_WB + l * D_ + kc * 128 + tid] = w;
    }
    __syncthreads();
    const float* W = sel ? Wv : Wk;
    float acc = 0.f;
    #pragma unroll 8
    for (int j = 0; j < 128; ++j) acc = fmaf(sx[j], W[(kc * 128 + j) * P_ + tid], acc);
    ws[OFF_AKVP + ((kc * 2 + sel) * 32 + l) * P_ + tid] = acc;
}

// ---- L6: tail per l: logits + softmax + EP + evo GEMM + LN_in. grid 32 x 512 ----
__global__ __launch_bounds__(512) void k_tail(
    const float* __restrict__ bk, const float* __restrict__ bv,
    const float* __restrict__ Wo, const float* __restrict__ bo,
    const float* __restrict__ g_in, const float* __restrict__ b_in,
    float* __restrict__ out_fa, float* __restrict__ ws)
{
    __shared__ __align__(16) float sq[512];
    __shared__ float slg[32];
    __shared__ float sfa[32];
    __shared__ __align__(16) float sep[512];
    __shared__ float buf[8];
    int l = blockIdx.x, tid = threadIdx.x, wv = tid >> 6, lane = tid & 63;
    sq[tid] = ws[OFF_QUERY + l * P_ + tid];
    __syncthreads();

    const float4* sq4 = (const float4*)sq;
    const float4* bk4 = (const float4*)bk;
    float4 q0 = sq4[lane * 2], q1 = sq4[lane * 2 + 1];
    float4 kb0 = bk4[lane * 2], kb1 = bk4[lane * 2 + 1];
    #pragma unroll
    for (int gi = 0; gi < 4; ++gi) {
        int g = wv * 4 + gi;
        // key[g] = sum_kc AKVP[kc][0][g] + bk ; kc stride = 64*512
        float4 A = kb0, B = kb1;
        #pragma unroll
        for (int kc = 0; kc < 4; ++kc) {
            const float4* kr = (const float4*)(ws + OFF_AKVP + (kc * 64 + g) * P_);
            float4 a = kr[lane * 2], b = kr[lane * 2 + 1];
            A.x += a.x; A.y += a.y; A.z += a.z; A.w += a.w;
            B.x += b.x; B.y += b.y; B.z += b.z; B.w += b.w;
        }
        float sdot = A.x * q0.x + A.y * q0.y + A.z * q0.z + A.w * q0.w
                   + B.x * q1.x + B.y * q1.y + B.z * q1.z + B.w * q1.w;
        sdot = wred64(sdot);
        if (lane == 0) slg[g] = sdot * SCALE;
    }
    __syncthreads();
    if (tid < 32) {
        float mx = -1e30f;
        for (int i = 0; i < 32; ++i) mx = fmaxf(mx, slg[i]);
        float Ssm = 0.f;
        for (int i = 0; i < 32; ++i) Ssm += expf(slg[i] - mx);
        float f = expf(slg[tid] - mx) / Ssm;
        sfa[tid] = f;
        out_fa[l * 32 + tid] = f;
    }
    __syncthreads();

    // EP[p] = sum_j fa[j] * (sum_kc AKVP[kc][1][j][p] + bv[p])
    float bvp = bv[tid];
    float acc = 0.f;
    #pragma unroll 4
    for (int j = 0; j < 32; ++j) {
        float vs = ws[OFF_AKVP + (0 * 64 + 32 + j) * P_ + tid]
                 + ws[OFF_AKVP + (1 * 64 + 32 + j) * P_ + tid]
                 + ws[OFF_AKVP + (2 * 64 + 32 + j) * P_ + tid]
                 + ws[OFF_AKVP + (3 * 64 + 32 + j) * P_ + tid];
        acc = fmaf(sfa[j], vs + bvp, acc);
    }
    sep[tid] = acc;
    __syncthreads();

    float ev = 0.f;
    #pragma unroll 8
    for (int j = 0; j < D_; ++j) ev = fmaf(sep[j], Wo[j * D_ + tid], ev);
    float x = ws[OFF_WB + l * D_ + tid] + ev + bo[tid];
    float mean = bsum512(x, buf, tid) * (1.f / D_);
    float dx = x - mean;
    float var = bsum512(dx * dx, buf, tid) * (1.f / D_);
    ws[OFF_EVOLVED + l * D_ + tid] = dx * rsqrtf(var + EPS_) * g_in[tid] + b_in[tid];
}

// ---- L7: MLP1 split-K partials. grid 512 (l|hc|kc) x 512 ----
__global__ __launch_bounds__(512) void k_mlp1(
    const float* __restrict__ Wa1, float* __restrict__ ws)
{
    __shared__ float sx[128];
    int blk = blockIdx.x, tid = threadIdx.x;
    int l = blk & 31, hc = (blk >> 5) & 3, kc = blk >> 7;
    if (tid < 128) sx[tid] = ws[OFF_EVOLVED + l * D_ + kc * 128 + tid];
    __syncthreads();
    int h = hc * 512 + tid;
    float acc = 0.f;
    #pragma unroll 8
    for (int j = 0; j < 128; ++j) acc = fmaf(sx[j], Wa1[(kc * 128 + j) * H_ + h], acc);
    ws[OFF_AH1P + (kc * 32 + l) * H_ + h] = acc;
}

// ---- L8: MLP2 split-K partials (relu+bias on the fly). grid 512 (l|kc) x 512 ----
__global__ __launch_bounds__(512) void k_mlp2(
    const float* __restrict__ Wa2, const float* __restrict__ ba1,
    float* __restrict__ ws)
{
    __shared__ float sh[128];
    int blk = blockIdx.x, tid = threadIdx.x;
    int l = blk & 31, kc = blk >> 5;   // kc 0..15
    if (tid < 128) {
        int h = kc * 128 + tid;
        float a = ba1[h];
        #pragma unroll
        for (int k4 = 0; k4 < 4; ++k4) a += ws[OFF_AH1P + (k4 * 32 + l) * H_ + h];
        sh[tid] = fmaxf(a, 0.f);
    }
    __syncthreads();
    float acc = 0.f;
    #pragma unroll 8
    for (int j = 0; j < 128; ++j) acc = fmaf(sh[j], Wa2[(kc * 128 + j) * D_ + tid], acc);
    ws[OFF_AOUTP + (kc * 32 + l) * D_ + tid] = acc;
}

// ---- L9: LN_out -> aligned. grid 32 x 512 ----
__global__ __launch_bounds__(512) void k_lnout(
    const float* __restrict__ ba2, const float* __restrict__ g_out,
    const float* __restrict__ b_out, float* __restrict__ out_al,
    float* __restrict__ ws)
{
    __shared__ float buf[8];
    int l = blockIdx.x, tid = threadIdx.x;
    float x = ws[OFF_EVOLVED + l * D_ + tid] + ba2[tid];
    #pragma unroll
    for (int kc = 0; kc < 16; ++kc) x += ws[OFF_AOUTP + (kc * 32 + l) * D_ + tid];
    float mean = bsum512(x, buf, tid) * (1.f / D_);
    float dx = x - mean;
    float var = bsum512(dx * dx, buf, tid) * (1.f / D_);
    out_al[l * D_ + tid] = dx * rsqrtf(var + EPS_) * g_out[tid] + b_out[tid];
}

// ---- L10: aligned_prompts broadcast, 64 MB write. grid 4096 x 256 ----
__global__ __launch_bounds__(256) void k_bcast(float* __restrict__ out) {
    const float4* src = (const float4*)out;       // 4096 float4
    float4* dst = (float4*)(out + OFFO_AP);
    int idx = blockIdx.x * 256 + threadIdx.x;
    #pragma unroll
    for (int k = 0; k < 4; ++k) {
        int v = idx + k * 1048576;
        dst[v] = src[v & 4095];
    }
}

extern "C" void kernel_launch(void* const* d_in, const int* in_sizes, int n_in,
                              void* d_out, int out_size, void* d_ws, size_t ws_size,
                              hipStream_t stream) {
    const float* base = (const float*)d_in[0];
    const float* np   = (const float*)d_in[1];
    const float* te   = (const float*)d_in[2];
    const float* Wt   = (const float*)d_in[3];
    const float* bt   = (const float*)d_in[4];
    const float* Wq   = (const float*)d_in[5];
    const float* bq   = (const float*)d_in[6];
    const float* Wk   = (const float*)d_in[7];
    const float* bk   = (const float*)d_in[8];
    const float* Wv   = (const float*)d_in[9];
    const float* bv   = (const float*)d_in[10];
    const float* Wo   = (const float*)d_in[11];
    const float* bo   = (const float*)d_in[12];
    const float* Wa1  = (const float*)d_in[13];
    const float* ba1  = (const float*)d_in[14];
    const float* Wa2  = (const float*)d_in[15];
    const float* ba2  = (const float*)d_in[16];
    const float* g_in = (const float*)d_in[17];
    const float* b_in = (const float*)d_in[18];
    const float* g_out= (const float*)d_in[19];
    const float* b_out= (const float*)d_in[20];
    float* out = (float*)d_out;
    float* ws = out + OFFO_AP;

    hipLaunchKernelGGL(k_aq_sb, dim3(1156),    dim3(512), 0, stream, base, np, te, Wq, Wt, ws);
    hipLaunchKernelGGL(k_prep,  dim3(64),      dim3(512), 0, stream, Wk, bk, bq, bt, ws);
    hipLaunchKernelGGL(k_uv,    dim3(1024),    dim3(512), 0, stream, ws);
    hipLaunchKernelGGL(k_part,  dim3(32, 32),  dim3(128), 0, stream, base, out + OFFO_TW, ws);
    hipLaunchKernelGGL(k_kv,    dim3(256),     dim3(512), 0, stream, Wk, Wv, ws);
    hipLaunchKernelGGL(k_tail,  dim3(32),      dim3(512), 0, stream, bk, bv, Wo, bo, g_in, b_in, out + OFFO_FA, ws);
    hipLaunchKernelGGL(k_mlp1,  dim3(512),     dim3(512), 0, stream, Wa1, ws);
    hipLaunchKernelGGL(k_mlp2,  dim3(512),     dim3(512), 0, stream, Wa2, ba1, ws);
    hipLaunchKernelGGL(k_lnout, dim3(32),      dim3(512), 0, stream, ba2, g_out, b_out, out + OFFO_AL, ws);
    hipLaunchKernelGGL(k_bcast, dim3(4096),    dim3(256), 0, stream, out);
}

// Round 4
// 274.008 us; speedup vs baseline: 2.4044x; 1.0796x over previous
//
#include <hip/hip_runtime.h>

// RainbowEvolution T=1024 L=32 D=512 P=512 H=2048. fp32 in / fp32 out.
// R9: R8b with k_tail (46us, 2.6% occupancy latency chain) split into
// k_kv_ep / k_attn / k_evo / k_lnin (13 launches total). Split-K partials
// everywhere, no atomics, no zero pass. Base scan overlapped with query
// GEMM in L1. Task softmax recomputed redundantly in k_part.
// Scratch in d_out's aligned_prompts region; bcast (last) overwrites it.

static constexpr int T_ = 1024, L_ = 32, D_ = 512, P_ = 512, H_ = 2048;
static constexpr float SCALE = 0.04419417382415922f; // 1/sqrt(512)
static constexpr float EPS_ = 1e-5f;

// out layout (fp32 offsets): aligned, aligned_prompts, task_weights, feature_attn
static constexpr int OFFO_AL = 0;
static constexpr int OFFO_AP = 16384;
static constexpr int OFFO_TW = 16384 + 16777216;   // 16793600
static constexpr int OFFO_FA = OFFO_TW + 1024;     // 16794624

// scratch (fp32 offsets into ws = out + OFFO_AP)
static constexpr int OFF_SB      = 0;        // [1024][512] sum_l base
static constexpr int OFF_AQP     = 524288;   // [4kc][33][512] query|tv partials
static constexpr int OFF_QUERY   = 591872;   // [32][512]
static constexpr int OFF_WKTV    = 608256;   // [512]
static constexpr int OFF_WKPQ    = 608768;   // [512]
static constexpr int OFF_SC      = 609280;   // [64] scalars: bkt, bkq
static constexpr int OFF_U       = 609344;   // [1024]
static constexpr int OFF_V       = 610368;   // [1024]
static constexpr int OFF_PART    = 611392;   // [32ch][32l][512]
static constexpr int OFF_WB      = 1135680;  // [32][512]
static constexpr int OFF_AKVP    = 1152064;  // [4kc][2sel][32][512]
static constexpr int OFF_EVOLVED = 1283136;  // [32][512]
static constexpr int OFF_AH1P    = 1299520;  // [4kc][32][2048]
static constexpr int OFF_AOUTP   = 1561664;  // [16kc][32][512]
static constexpr int OFF_KEY     = 1823808;  // [32][512] final keys (+bk)
static constexpr int OFF_VAL     = 1840192;  // [32][512] final vals (+bv)
static constexpr int OFF_EP2     = 1856576;  // [32][512] evolved_proj
static constexpr int OFF_AEVOP   = 1872960;  // [4kc][32][512] evo partials

// ---- reductions ----
__device__ __forceinline__ float wred64(float v) {
    #pragma unroll
    for (int off = 32; off > 0; off >>= 1) v += __shfl_down(v, off, 64);
    return v;
}
__device__ __forceinline__ float wmax64(float v) {
    #pragma unroll
    for (int off = 32; off > 0; off >>= 1) v = fmaxf(v, __shfl_down(v, off, 64));
    return v;
}
// 512-thread block sum (leading sync protects buf reuse)
__device__ __forceinline__ float bsum512(float v, float* buf, int tid) {
    v = wred64(v);
    __syncthreads();
    if ((tid & 63) == 0) buf[tid >> 6] = v;
    __syncthreads();
    float s = 0.f;
    #pragma unroll
    for (int i = 0; i < 8; ++i) s += buf[i];
    return s;
}
// 128-thread block sum/max
__device__ __forceinline__ float bsum128(float v, float* buf, int tid) {
    v = wred64(v);
    __syncthreads();
    if ((tid & 63) == 0) buf[tid >> 6] = v;
    __syncthreads();
    return buf[0] + buf[1];
}
__device__ __forceinline__ float bmax128(float v, float* buf, int tid) {
    v = wmax64(v);
    __syncthreads();
    if ((tid & 63) == 0) buf[tid >> 6] = v;
    __syncthreads();
    return fmaxf(buf[0], buf[1]);
}

// ---- L1: AQ partials GEMM (blocks 0..131) + SB scan (blocks 132..1155) ----
__global__ __launch_bounds__(512) void k_aq_sb(
    const float* __restrict__ base, const float* __restrict__ np_,
    const float* __restrict__ te, const float* __restrict__ Wq,
    const float* __restrict__ Wt, float* __restrict__ ws)
{
    __shared__ __align__(16) float4 smem4[512];   // 8 KB
    int blk = blockIdx.x, tid = threadIdx.x;
    if (blk < 132) {
        float* sx = (float*)smem4;                // 128 floats
        int b = blk % 33, kc = blk / 33;
        const float* x = (b < 32) ? (np_ + b * D_) : te;
        const float* W = (b < 32) ? Wq : Wt;
        if (tid < 128) sx[tid] = x[kc * 128 + tid];
        __syncthreads();
        float acc = 0.f;
        #pragma unroll 8
        for (int j = 0; j < 128; ++j) acc = fmaf(sx[j], W[(kc * 128 + j) * P_ + tid], acc);
        ws[OFF_AQP + (kc * 33 + b) * P_ + tid] = acc;
    } else {
        int t = blk - 132;
        const float4* bp = (const float4*)(base + (size_t)t * (L_ * D_));
        int d4 = tid & 127, lq = tid >> 7;
        float4 acc = make_float4(0.f, 0.f, 0.f, 0.f);
        #pragma unroll
        for (int i = 0; i < 8; ++i) {
            int l = i * 4 + lq;
            float4 v = bp[l * 128 + d4];
            acc.x += v.x; acc.y += v.y; acc.z += v.z; acc.w += v.w;
        }
        smem4[tid] = acc;
        __syncthreads();
        if (tid < 128) {
            float4 a = smem4[tid], b2 = smem4[tid + 128];
            float4 c = smem4[tid + 256], d2 = smem4[tid + 384];
            float4 r;
            r.x = a.x + b2.x + c.x + d2.x;
            r.y = a.y + b2.y + c.y + d2.y;
            r.z = a.z + b2.z + c.z + d2.z;
            r.w = a.w + b2.w + c.w + d2.w;
            ((float4*)(ws + OFF_SB + t * D_))[tid] = r;
        }
    }
}

// ---- L2: QUERY rows, TV/PQ (redundant), WKTV/WKPQ, bkt/bkq. grid 64 x 512 ----
__global__ __launch_bounds__(512) void k_prep(
    const float* __restrict__ Wk, const float* __restrict__ bk,
    const float* __restrict__ bq, const float* __restrict__ bt,
    float* __restrict__ ws)
{
    __shared__ __align__(16) float stv[512];
    __shared__ __align__(16) float spq[512];
    __shared__ float buf[8];
    int blk = blockIdx.x, tid = threadIdx.x;

    // TV (redundant per block): tanh(sum_kc AQP[kc][32] + bt)
    float a = 0.f;
    #pragma unroll
    for (int kc = 0; kc < 4; ++kc) a += ws[OFF_AQP + (kc * 33 + 32) * P_ + tid];
    stv[tid] = tanhf(a + bt[tid]);

    // PQ (redundant): mean_l (sum_kc AQP[kc][l]) + bq
    float b = 0.f;
    #pragma unroll 4
    for (int kc = 0; kc < 4; ++kc)
        for (int l = 0; l < 32; ++l) b += ws[OFF_AQP + (kc * 33 + l) * P_ + tid];
    spq[tid] = b * (1.f / 32.f) + bq[tid];

    // QUERY rows (blocks 0..31)
    if (blk < 32) {
        float q = bq[tid];
        #pragma unroll
        for (int kc = 0; kc < 4; ++kc) q += ws[OFF_AQP + (kc * 33 + blk) * P_ + tid];
        ws[OFF_QUERY + blk * P_ + tid] = q;
    }
    __syncthreads();

    // WKTV/WKPQ: wave per d (8 d's per block)
    int wv = tid >> 6, lane = tid & 63;
    int d = blk * 8 + wv;
    const float4* row = (const float4*)(Wk + d * P_);
    const float4* tv4 = (const float4*)stv;
    const float4* pq4 = (const float4*)spq;
    float4 r0 = row[lane * 2], r1 = row[lane * 2 + 1];
    float4 t0 = tv4[lane * 2], t1 = tv4[lane * 2 + 1];
    float4 q0 = pq4[lane * 2], q1 = pq4[lane * 2 + 1];
    float pa = r0.x * t0.x + r0.y * t0.y + r0.z * t0.z + r0.w * t0.w
             + r1.x * t1.x + r1.y * t1.y + r1.z * t1.z + r1.w * t1.w;
    float pb = r0.x * q0.x + r0.y * q0.y + r0.z * q0.z + r0.w * q0.w
             + r1.x * q1.x + r1.y * q1.y + r1.z * q1.z + r1.w * q1.w;
    pa = wred64(pa); pb = wred64(pb);
    if (lane == 0) { ws[OFF_WKTV + d] = pa; ws[OFF_WKPQ + d] = pb; }

    // bkt / bkq (block 63)
    if (blk == 63) {
        float bkf = bk[tid];
        float s1 = bsum512(bkf * stv[tid], buf, tid);
        float s2 = bsum512(bkf * spq[tid], buf, tid);
        if (tid == 0) { ws[OFF_SC] = s1; ws[OFF_SC + 1] = s2; }
    }
}

// ---- L3: U[t], V[t]. grid 1024 x 512 ----
__global__ __launch_bounds__(512) void k_uv(float* __restrict__ ws)
{
    __shared__ float buf[8];
    int t = blockIdx.x, tid = threadIdx.x;
    float sb = ws[OFF_SB + t * D_ + tid];
    float a = bsum512(sb * ws[OFF_WKTV + tid], buf, tid);
    float b = bsum512(sb * ws[OFF_WKPQ + tid], buf, tid);
    if (tid == 0) {
        ws[OFF_U + t] = a * (1.f / L_);
        ws[OFF_V + t] = b * (1.f / L_);
    }
}

// ---- L4: redundant task-softmax + weighted pooling PART. grid(32l,32ch) x128 ----
__global__ __launch_bounds__(128) void k_part(
    const float* __restrict__ base, float* __restrict__ out_tw,
    float* __restrict__ ws)
{
    __shared__ float sC[1024];
    __shared__ float rbuf[2];
    int l = blockIdx.x, ch = blockIdx.y, tid = threadIdx.x;
    float bkt = ws[OFF_SC], bkq = ws[OFF_SC + 1];

    float u[8], v[8], s1[8], tw1[8], tw[8];
    #pragma unroll
    for (int i = 0; i < 8; ++i) {
        int t = i * 128 + tid;
        u[i] = ws[OFF_U + t];
        v[i] = ws[OFF_V + t];
    }
    // softmax 1 -> tw1
    float lmax = -1e30f;
    #pragma unroll
    for (int i = 0; i < 8; ++i) { s1[i] = (u[i] + bkt) * SCALE; lmax = fmaxf(lmax, s1[i]); }
    float gmax = bmax128(lmax, rbuf, tid);
    float ls = 0.f;
    #pragma unroll
    for (int i = 0; i < 8; ++i) { s1[i] = expf(s1[i] - gmax); ls += s1[i]; }
    float gs = bsum128(ls, rbuf, tid);
    #pragma unroll
    for (int i = 0; i < 8; ++i) tw1[i] = s1[i] / gs;
    // softmax 2 (task_attn)
    lmax = -1e30f;
    #pragma unroll
    for (int i = 0; i < 8; ++i) {
        s1[i] = ((1.f + tw1[i]) * v[i] + bkq) * SCALE;
        lmax = fmaxf(lmax, s1[i]);
    }
    gmax = bmax128(lmax, rbuf, tid);
    ls = 0.f;
    #pragma unroll
    for (int i = 0; i < 8; ++i) { s1[i] = expf(s1[i] - gmax); ls += s1[i]; }
    gs = bsum128(ls, rbuf, tid);
    float lsum = 0.f;
    #pragma unroll
    for (int i = 0; i < 8; ++i) {
        tw[i] = 0.5f * tw1[i] + 0.5f * (s1[i] / gs);
        lsum += tw[i];
    }
    float S = bsum128(lsum, rbuf, tid);
    S = fmaxf(S, 1e-6f);
    #pragma unroll
    for (int i = 0; i < 8; ++i) {
        int t = i * 128 + tid;
        float twn = tw[i] / S;
        sC[t] = twn * (1.f + tw1[i]);
        if (l == 0 && ch == 0) out_tw[t] = twn;
    }
    __syncthreads();

    // PART[ch][l][:] = sum_{i<32} C[ch*32+i] * base[ch*32+i, l, :]
    float4 acc = make_float4(0.f, 0.f, 0.f, 0.f);
    for (int i = 0; i < 32; ++i) {
        int t = ch * 32 + i;
        float c = sC[t];
        float4 bv4 = ((const float4*)(base + ((size_t)t * L_ + l) * D_))[tid];
        acc.x = fmaf(c, bv4.x, acc.x);
        acc.y = fmaf(c, bv4.y, acc.y);
        acc.z = fmaf(c, bv4.z, acc.z);
        acc.w = fmaf(c, bv4.w, acc.w);
    }
    ((float4*)(ws + OFF_PART + (ch * 32 + l) * D_))[tid] = acc;
}

// ---- L5: WB reduce + split-K KV GEMM partials. grid 256 (l|sel|kc) x 512 ----
__global__ __launch_bounds__(512) void k_kv(
    const float* __restrict__ Wk, const float* __restrict__ Wv,
    float* __restrict__ ws)
{
    __shared__ float part[512];
    __shared__ float sx[128];
    int blk = blockIdx.x, tid = threadIdx.x;
    int l = blk & 31, sel = (blk >> 5) & 1, kc = blk >> 6;
    int p = tid & 127, c = tid >> 7;
    float s = 0.f;
    #pragma unroll
    for (int ch = c; ch < 32; ch += 4)
        s += ws[OFF_PART + (ch * 32 + l) * D_ + kc * 128 + p];
    part[tid] = s;
    __syncthreads();
    if (tid < 128) {
        float w = part[tid] + part[tid + 128] + part[tid + 256] + part[tid + 384];
        sx[tid] = w;
        if (sel == 0) ws[OFF_WB + l * D_ + kc * 128 + tid] = w;
    }
    __syncthreads();
    const float* W = sel ? Wv : Wk;
    float acc = 0.f;
    #pragma unroll 8
    for (int j = 0; j < 128; ++j) acc = fmaf(sx[j], W[(kc * 128 + j) * P_ + tid], acc);
    ws[OFF_AKVP + ((kc * 2 + sel) * 32 + l) * P_ + tid] = acc;
}

// ---- L6: KEY/VAL = sum_kc AKVP + bias. grid 64 (l|sel) x 512 ----
__global__ __launch_bounds__(512) void k_kv_ep(
    const float* __restrict__ bk, const float* __restrict__ bv,
    float* __restrict__ ws)
{
    int blk = blockIdx.x, tid = threadIdx.x;
    int l = blk & 31, sel = blk >> 5;
    float s = sel ? bv[tid] : bk[tid];
    #pragma unroll
    for (int kc = 0; kc < 4; ++kc)
        s += ws[OFF_AKVP + ((kc * 2 + sel) * 32 + l) * P_ + tid];
    ws[(sel ? OFF_VAL : OFF_KEY) + l * P_ + tid] = s;
}

// ---- L7: logits + softmax + EP. grid 32 x 512 ----
__global__ __launch_bounds__(512) void k_attn(
    float* __restrict__ out_fa, float* __restrict__ ws)
{
    __shared__ __align__(16) float sq[512];
    __shared__ float slg[32];
    __shared__ float sfa[32];
    int l = blockIdx.x, tid = threadIdx.x, wv = tid >> 6, lane = tid & 63;
    sq[tid] = ws[OFF_QUERY + l * P_ + tid];
    __syncthreads();

    const float4* sq4 = (const float4*)sq;
    float4 q0 = sq4[lane * 2], q1 = sq4[lane * 2 + 1];
    #pragma unroll
    for (int gi = 0; gi < 4; ++gi) {
        int g = wv * 4 + gi;
        const float4* kr = (const float4*)(ws + OFF_KEY + g * P_);
        float4 a = kr[lane * 2], b = kr[lane * 2 + 1];
        float sdot = a.x * q0.x + a.y * q0.y + a.z * q0.z + a.w * q0.w
                   + b.x * q1.x + b.y * q1.y + b.z * q1.z + b.w * q1.w;
        sdot = wred64(sdot);
        if (lane == 0) slg[g] = sdot * SCALE;
    }
    __syncthreads();
    if (tid < 32) {
        float mx = -1e30f;
        for (int i = 0; i < 32; ++i) mx = fmaxf(mx, slg[i]);
        float Ssm = 0.f;
        for (int i = 0; i < 32; ++i) Ssm += expf(slg[i] - mx);
        float f = expf(slg[tid] - mx) / Ssm;
        sfa[tid] = f;
        out_fa[l * 32 + tid] = f;
    }
    __syncthreads();

    float acc = 0.f;
    #pragma unroll 8
    for (int j = 0; j < 32; ++j)
        acc = fmaf(sfa[j], ws[OFF_VAL + j * P_ + tid], acc);
    ws[OFF_EP2 + l * P_ + tid] = acc;
}

// ---- L8: split-K EP @ Wo partials. grid (32l, 4kc) x 512 ----
__global__ __launch_bounds__(512) void k_evo(
    const float* __restrict__ Wo, float* __restrict__ ws)
{
    __shared__ float sx[128];
    int l = blockIdx.x, kc = blockIdx.y, tid = threadIdx.x;
    if (tid < 128) sx[tid] = ws[OFF_EP2 + l * P_ + kc * 128 + tid];
    __syncthreads();
    float acc = 0.f;
    #pragma unroll 8
    for (int j = 0; j < 128; ++j) acc = fmaf(sx[j], Wo[(kc * 128 + j) * D_ + tid], acc);
    ws[OFF_AEVOP + (kc * 32 + l) * D_ + tid] = acc;
}

// ---- L9: LN_in -> EVOLVED. grid 32 x 512 ----
__global__ __launch_bounds__(512) void k_lnin(
    const float* __restrict__ bo, const float* __restrict__ g_in,
    const float* __restrict__ b_in, float* __restrict__ ws)
{
    __shared__ float buf[8];
    int l = blockIdx.x, tid = threadIdx.x;
    float x = ws[OFF_WB + l * D_ + tid] + bo[tid];
    #pragma unroll
    for (int kc = 0; kc < 4; ++kc) x += ws[OFF_AEVOP + (kc * 32 + l) * D_ + tid];
    float mean = bsum512(x, buf, tid) * (1.f / D_);
    float dx = x - mean;
    float var = bsum512(dx * dx, buf, tid) * (1.f / D_);
    ws[OFF_EVOLVED + l * D_ + tid] = dx * rsqrtf(var + EPS_) * g_in[tid] + b_in[tid];
}

// ---- L10: MLP1 split-K partials. grid 512 (l|hc|kc) x 512 ----
__global__ __launch_bounds__(512) void k_mlp1(
    const float* __restrict__ Wa1, float* __restrict__ ws)
{
    __shared__ float sx[128];
    int blk = blockIdx.x, tid = threadIdx.x;
    int l = blk & 31, hc = (blk >> 5) & 3, kc = blk >> 7;
    if (tid < 128) sx[tid] = ws[OFF_EVOLVED + l * D_ + kc * 128 + tid];
    __syncthreads();
    int h = hc * 512 + tid;
    float acc = 0.f;
    #pragma unroll 8
    for (int j = 0; j < 128; ++j) acc = fmaf(sx[j], Wa1[(kc * 128 + j) * H_ + h], acc);
    ws[OFF_AH1P + (kc * 32 + l) * H_ + h] = acc;
}

// ---- L11: MLP2 split-K partials (relu+bias on the fly). grid 512 (l|kc) x 512 ----
__global__ __launch_bounds__(512) void k_mlp2(
    const float* __restrict__ Wa2, const float* __restrict__ ba1,
    float* __restrict__ ws)
{
    __shared__ float sh[128];
    int blk = blockIdx.x, tid = threadIdx.x;
    int l = blk & 31, kc = blk >> 5;   // kc 0..15
    if (tid < 128) {
        int h = kc * 128 + tid;
        float a = ba1[h];
        #pragma unroll
        for (int k4 = 0; k4 < 4; ++k4) a += ws[OFF_AH1P + (k4 * 32 + l) * H_ + h];
        sh[tid] = fmaxf(a, 0.f);
    }
    __syncthreads();
    float acc = 0.f;
    #pragma unroll 8
    for (int j = 0; j < 128; ++j) acc = fmaf(sh[j], Wa2[(kc * 128 + j) * D_ + tid], acc);
    ws[OFF_AOUTP + (kc * 32 + l) * D_ + tid] = acc;
}

// ---- L12: LN_out -> aligned. grid 32 x 512 ----
__global__ __launch_bounds__(512) void k_lnout(
    const float* __restrict__ ba2, const float* __restrict__ g_out,
    const float* __restrict__ b_out, float* __restrict__ out_al,
    float* __restrict__ ws)
{
    __shared__ float buf[8];
    int l = blockIdx.x, tid = threadIdx.x;
    float x = ws[OFF_EVOLVED + l * D_ + tid] + ba2[tid];
    #pragma unroll
    for (int kc = 0; kc < 16; ++kc) x += ws[OFF_AOUTP + (kc * 32 + l) * D_ + tid];
    float mean = bsum512(x, buf, tid) * (1.f / D_);
    float dx = x - mean;
    float var = bsum512(dx * dx, buf, tid) * (1.f / D_);
    out_al[l * D_ + tid] = dx * rsqrtf(var + EPS_) * g_out[tid] + b_out[tid];
}

// ---- L13: aligned_prompts broadcast, 64 MB write. grid 4096 x 256 ----
__global__ __launch_bounds__(256) void k_bcast(float* __restrict__ out) {
    const float4* src = (const float4*)out;       // 4096 float4
    float4* dst = (float4*)(out + OFFO_AP);
    int idx = blockIdx.x * 256 + threadIdx.x;
    #pragma unroll
    for (int k = 0; k < 4; ++k) {
        int v = idx + k * 1048576;
        dst[v] = src[v & 4095];
    }
}

extern "C" void kernel_launch(void* const* d_in, const int* in_sizes, int n_in,
                              void* d_out, int out_size, void* d_ws, size_t ws_size,
                              hipStream_t stream) {
    const float* base = (const float*)d_in[0];
    const float* np   = (const float*)d_in[1];
    const float* te   = (const float*)d_in[2];
    const float* Wt   = (const float*)d_in[3];
    const float* bt   = (const float*)d_in[4];
    const float* Wq   = (const float*)d_in[5];
    const float* bq   = (const float*)d_in[6];
    const float* Wk   = (const float*)d_in[7];
    const float* bk   = (const float*)d_in[8];
    const float* Wv   = (const float*)d_in[9];
    const float* bv   = (const float*)d_in[10];
    const float* Wo   = (const float*)d_in[11];
    const float* bo   = (const float*)d_in[12];
    const float* Wa1  = (const float*)d_in[13];
    const float* ba1  = (const float*)d_in[14];
    const float* Wa2  = (const float*)d_in[15];
    const float* ba2  = (const float*)d_in[16];
    const float* g_in = (const float*)d_in[17];
    const float* b_in = (const float*)d_in[18];
    const float* g_out= (const float*)d_in[19];
    const float* b_out= (const float*)d_in[20];
    float* out = (float*)d_out;
    float* ws = out + OFFO_AP;

    hipLaunchKernelGGL(k_aq_sb, dim3(1156),    dim3(512), 0, stream, base, np, te, Wq, Wt, ws);
    hipLaunchKernelGGL(k_prep,  dim3(64),      dim3(512), 0, stream, Wk, bk, bq, bt, ws);
    hipLaunchKernelGGL(k_uv,    dim3(1024),    dim3(512), 0, stream, ws);
    hipLaunchKernelGGL(k_part,  dim3(32, 32),  dim3(128), 0, stream, base, out + OFFO_TW, ws);
    hipLaunchKernelGGL(k_kv,    dim3(256),     dim3(512), 0, stream, Wk, Wv, ws);
    hipLaunchKernelGGL(k_kv_ep, dim3(64),      dim3(512), 0, stream, bk, bv, ws);
    hipLaunchKernelGGL(k_attn,  dim3(32),      dim3(512), 0, stream, out + OFFO_FA, ws);
    hipLaunchKernelGGL(k_evo,   dim3(32, 4),   dim3(512), 0, stream, Wo, ws);
    hipLaunchKernelGGL(k_lnin,  dim3(32),      dim3(512), 0, stream, bo, g_in, b_in, ws);
    hipLaunchKernelGGL(k_mlp1,  dim3(512),     dim3(512), 0, stream, Wa1, ws);
    hipLaunchKernelGGL(k_mlp2,  dim3(512),     dim3(512), 0, stream, Wa2, ba1, ws);
    hipLaunchKernelGGL(k_lnout, dim3(32),      dim3(512), 0, stream, ba2, g_out, b_out, out + OFFO_AL, ws);
    hipLaunchKernelGGL(k_bcast, dim3(4096),    dim3(256), 0, stream, out);
}

// Round 5
// 258.393 us; speedup vs baseline: 2.5497x; 1.0604x over previous
//
#include <hip/hip_runtime.h>

// RainbowEvolution T=1024 L=32 D=512 P=512 H=2048. fp32 in / fp32 out.
// R10: R9 minus 2 launches (11 total), plus:
//  - L1 prewarms Wo/Wa1/Wa2/Wk/Wv (11MB) into L3 alongside base scan
//    (R8b calibration: 32-block kernel streaming cold weights = 46us;
//     per-CU BW ~10B/cy caps low-block kernels; L3 is thrashed per-iter).
//  - k_evo kc 4->8 (256 blocks, 64-deep loops).
//  - k_kv_ep fused into k_attn (inline partial sums + bias).
//  - LN_in fused into k_mlp1 / k_lnout (EVOLVED never materialized).
// Split-K partials everywhere, no atomics, no zero pass.
// Scratch in d_out's aligned_prompts region; bcast (last) overwrites it.

static constexpr int T_ = 1024, L_ = 32, D_ = 512, P_ = 512, H_ = 2048;
static constexpr float SCALE = 0.04419417382415922f; // 1/sqrt(512)
static constexpr float EPS_ = 1e-5f;

// out layout (fp32 offsets): aligned, aligned_prompts, task_weights, feature_attn
static constexpr int OFFO_AL = 0;
static constexpr int OFFO_AP = 16384;
static constexpr int OFFO_TW = 16384 + 16777216;   // 16793600
static constexpr int OFFO_FA = OFFO_TW + 1024;     // 16794624

// scratch (fp32 offsets into ws = out + OFFO_AP)
static constexpr int OFF_SB      = 0;        // [1024][512] sum_l base
static constexpr int OFF_AQP     = 524288;   // [4kc][33][512] query|tv partials
static constexpr int OFF_QUERY   = 591872;   // [32][512]
static constexpr int OFF_WKTV    = 608256;   // [512]
static constexpr int OFF_WKPQ    = 608768;   // [512]
static constexpr int OFF_SC      = 609280;   // [64] scalars: bkt, bkq
static constexpr int OFF_U       = 609344;   // [1024]
static constexpr int OFF_V       = 610368;   // [1024]
static constexpr int OFF_PART    = 611392;   // [32ch][32l][512]
static constexpr int OFF_WB      = 1135680;  // [32][512]
static constexpr int OFF_AKVP    = 1152064;  // [4kc][2sel][32][512]
static constexpr int OFF_EP2     = 1283136;  // [32][512] evolved_proj
static constexpr int OFF_AH1P    = 1299520;  // [4kc][32][2048]
static constexpr int OFF_AOUTP   = 1561664;  // [16kc][32][512]
static constexpr int OFF_AEVOP   = 1823808;  // [8kc][32][512]
static constexpr int OFF_DUMMY   = 1954880;  // [176*512] prewarm sink

// ---- reductions ----
__device__ __forceinline__ float wred64(float v) {
    #pragma unroll
    for (int off = 32; off > 0; off >>= 1) v += __shfl_down(v, off, 64);
    return v;
}
__device__ __forceinline__ float wmax64(float v) {
    #pragma unroll
    for (int off = 32; off > 0; off >>= 1) v = fmaxf(v, __shfl_down(v, off, 64));
    return v;
}
__device__ __forceinline__ float bsum512(float v, float* buf, int tid) {
    v = wred64(v);
    __syncthreads();
    if ((tid & 63) == 0) buf[tid >> 6] = v;
    __syncthreads();
    float s = 0.f;
    #pragma unroll
    for (int i = 0; i < 8; ++i) s += buf[i];
    return s;
}
__device__ __forceinline__ float bsum128(float v, float* buf, int tid) {
    v = wred64(v);
    __syncthreads();
    if ((tid & 63) == 0) buf[tid >> 6] = v;
    __syncthreads();
    return buf[0] + buf[1];
}
__device__ __forceinline__ float bmax128(float v, float* buf, int tid) {
    v = wmax64(v);
    __syncthreads();
    if ((tid & 63) == 0) buf[tid >> 6] = v;
    __syncthreads();
    return fmaxf(buf[0], buf[1]);
}

// ---- L1: prewarm weights (0..175) + AQ partial GEMM (176..307) + SB scan ----
__global__ __launch_bounds__(512) void k_aq_sb(
    const float* __restrict__ base, const float* __restrict__ np_,
    const float* __restrict__ te, const float* __restrict__ Wq,
    const float* __restrict__ Wt, const float* __restrict__ Wk,
    const float* __restrict__ Wv, const float* __restrict__ Wo,
    const float* __restrict__ Wa1, const float* __restrict__ Wa2,
    float* __restrict__ ws)
{
    __shared__ __align__(16) float4 smem4[512];   // 8 KB
    int blk = blockIdx.x, tid = threadIdx.x;
    if (blk < 176) {
        // prewarm: stream 64KB/block of weights into L3 (per-thread sink
        // stores keep every load live against DCE)
        const float* src;
        int pw = blk;
        if (pw < 16)       src = Wo  + pw * 16384;
        else if (pw < 80)  src = Wa1 + (pw - 16) * 16384;
        else if (pw < 144) src = Wa2 + (pw - 80) * 16384;
        else if (pw < 160) src = Wk  + (pw - 144) * 16384;
        else               src = Wv  + (pw - 160) * 16384;
        const float4* s4 = (const float4*)src;
        float4 acc = make_float4(0.f, 0.f, 0.f, 0.f);
        #pragma unroll
        for (int i = 0; i < 8; ++i) {
            float4 v = s4[i * 512 + tid];
            acc.x += v.x; acc.y += v.y; acc.z += v.z; acc.w += v.w;
        }
        ws[OFF_DUMMY + pw * 512 + tid] = acc.x + acc.y + acc.z + acc.w;
    } else if (blk < 308) {
        float* sx = (float*)smem4;                // 128 floats
        int b = (blk - 176) % 33, kc = (blk - 176) / 33;
        const float* x = (b < 32) ? (np_ + b * D_) : te;
        const float* W = (b < 32) ? Wq : Wt;
        if (tid < 128) sx[tid] = x[kc * 128 + tid];
        __syncthreads();
        float acc = 0.f;
        #pragma unroll 8
        for (int j = 0; j < 128; ++j) acc = fmaf(sx[j], W[(kc * 128 + j) * P_ + tid], acc);
        ws[OFF_AQP + (kc * 33 + b) * P_ + tid] = acc;
    } else {
        int t = blk - 308;
        const float4* bp = (const float4*)(base + (size_t)t * (L_ * D_));
        int d4 = tid & 127, lq = tid >> 7;
        float4 acc = make_float4(0.f, 0.f, 0.f, 0.f);
        #pragma unroll
        for (int i = 0; i < 8; ++i) {
            int l = i * 4 + lq;
            float4 v = bp[l * 128 + d4];
            acc.x += v.x; acc.y += v.y; acc.z += v.z; acc.w += v.w;
        }
        smem4[tid] = acc;
        __syncthreads();
        if (tid < 128) {
            float4 a = smem4[tid], b2 = smem4[tid + 128];
            float4 c = smem4[tid + 256], d2 = smem4[tid + 384];
            float4 r;
            r.x = a.x + b2.x + c.x + d2.x;
            r.y = a.y + b2.y + c.y + d2.y;
            r.z = a.z + b2.z + c.z + d2.z;
            r.w = a.w + b2.w + c.w + d2.w;
            ((float4*)(ws + OFF_SB + t * D_))[tid] = r;
        }
    }
}

// ---- L2: QUERY rows, TV/PQ (redundant), WKTV/WKPQ, bkt/bkq. grid 64 x 512 ----
__global__ __launch_bounds__(512) void k_prep(
    const float* __restrict__ Wk, const float* __restrict__ bk,
    const float* __restrict__ bq, const float* __restrict__ bt,
    float* __restrict__ ws)
{
    __shared__ __align__(16) float stv[512];
    __shared__ __align__(16) float spq[512];
    __shared__ float buf[8];
    int blk = blockIdx.x, tid = threadIdx.x;

    float a = 0.f;
    #pragma unroll
    for (int kc = 0; kc < 4; ++kc) a += ws[OFF_AQP + (kc * 33 + 32) * P_ + tid];
    stv[tid] = tanhf(a + bt[tid]);

    float b = 0.f;
    #pragma unroll 4
    for (int kc = 0; kc < 4; ++kc)
        for (int l = 0; l < 32; ++l) b += ws[OFF_AQP + (kc * 33 + l) * P_ + tid];
    spq[tid] = b * (1.f / 32.f) + bq[tid];

    if (blk < 32) {
        float q = bq[tid];
        #pragma unroll
        for (int kc = 0; kc < 4; ++kc) q += ws[OFF_AQP + (kc * 33 + blk) * P_ + tid];
        ws[OFF_QUERY + blk * P_ + tid] = q;
    }
    __syncthreads();

    int wv = tid >> 6, lane = tid & 63;
    int d = blk * 8 + wv;
    const float4* row = (const float4*)(Wk + d * P_);
    const float4* tv4 = (const float4*)stv;
    const float4* pq4 = (const float4*)spq;
    float4 r0 = row[lane * 2], r1 = row[lane * 2 + 1];
    float4 t0 = tv4[lane * 2], t1 = tv4[lane * 2 + 1];
    float4 q0 = pq4[lane * 2], q1 = pq4[lane * 2 + 1];
    float pa = r0.x * t0.x + r0.y * t0.y + r0.z * t0.z + r0.w * t0.w
             + r1.x * t1.x + r1.y * t1.y + r1.z * t1.z + r1.w * t1.w;
    float pb = r0.x * q0.x + r0.y * q0.y + r0.z * q0.z + r0.w * q0.w
             + r1.x * q1.x + r1.y * q1.y + r1.z * q1.z + r1.w * q1.w;
    pa = wred64(pa); pb = wred64(pb);
    if (lane == 0) { ws[OFF_WKTV + d] = pa; ws[OFF_WKPQ + d] = pb; }

    if (blk == 63) {
        float bkf = bk[tid];
        float s1 = bsum512(bkf * stv[tid], buf, tid);
        float s2 = bsum512(bkf * spq[tid], buf, tid);
        if (tid == 0) { ws[OFF_SC] = s1; ws[OFF_SC + 1] = s2; }
    }
}

// ---- L3: U[t], V[t]. grid 1024 x 512 ----
__global__ __launch_bounds__(512) void k_uv(float* __restrict__ ws)
{
    __shared__ float buf[8];
    int t = blockIdx.x, tid = threadIdx.x;
    float sb = ws[OFF_SB + t * D_ + tid];
    float a = bsum512(sb * ws[OFF_WKTV + tid], buf, tid);
    float b = bsum512(sb * ws[OFF_WKPQ + tid], buf, tid);
    if (tid == 0) {
        ws[OFF_U + t] = a * (1.f / L_);
        ws[OFF_V + t] = b * (1.f / L_);
    }
}

// ---- L4: redundant task-softmax + weighted pooling PART. grid(32l,32ch) x128 ----
__global__ __launch_bounds__(128) void k_part(
    const float* __restrict__ base, float* __restrict__ out_tw,
    float* __restrict__ ws)
{
    __shared__ float sC[1024];
    __shared__ float rbuf[2];
    int l = blockIdx.x, ch = blockIdx.y, tid = threadIdx.x;
    float bkt = ws[OFF_SC], bkq = ws[OFF_SC + 1];

    float u[8], v[8], s1[8], tw1[8], tw[8];
    #pragma unroll
    for (int i = 0; i < 8; ++i) {
        int t = i * 128 + tid;
        u[i] = ws[OFF_U + t];
        v[i] = ws[OFF_V + t];
    }
    float lmax = -1e30f;
    #pragma unroll
    for (int i = 0; i < 8; ++i) { s1[i] = (u[i] + bkt) * SCALE; lmax = fmaxf(lmax, s1[i]); }
    float gmax = bmax128(lmax, rbuf, tid);
    float ls = 0.f;
    #pragma unroll
    for (int i = 0; i < 8; ++i) { s1[i] = expf(s1[i] - gmax); ls += s1[i]; }
    float gs = bsum128(ls, rbuf, tid);
    #pragma unroll
    for (int i = 0; i < 8; ++i) tw1[i] = s1[i] / gs;
    lmax = -1e30f;
    #pragma unroll
    for (int i = 0; i < 8; ++i) {
        s1[i] = ((1.f + tw1[i]) * v[i] + bkq) * SCALE;
        lmax = fmaxf(lmax, s1[i]);
    }
    gmax = bmax128(lmax, rbuf, tid);
    ls = 0.f;
    #pragma unroll
    for (int i = 0; i < 8; ++i) { s1[i] = expf(s1[i] - gmax); ls += s1[i]; }
    gs = bsum128(ls, rbuf, tid);
    float lsum = 0.f;
    #pragma unroll
    for (int i = 0; i < 8; ++i) {
        tw[i] = 0.5f * tw1[i] + 0.5f * (s1[i] / gs);
        lsum += tw[i];
    }
    float S = bsum128(lsum, rbuf, tid);
    S = fmaxf(S, 1e-6f);
    #pragma unroll
    for (int i = 0; i < 8; ++i) {
        int t = i * 128 + tid;
        float twn = tw[i] / S;
        sC[t] = twn * (1.f + tw1[i]);
        if (l == 0 && ch == 0) out_tw[t] = twn;
    }
    __syncthreads();

    float4 acc = make_float4(0.f, 0.f, 0.f, 0.f);
    for (int i = 0; i < 32; ++i) {
        int t = ch * 32 + i;
        float c = sC[t];
        float4 bv4 = ((const float4*)(base + ((size_t)t * L_ + l) * D_))[tid];
        acc.x = fmaf(c, bv4.x, acc.x);
        acc.y = fmaf(c, bv4.y, acc.y);
        acc.z = fmaf(c, bv4.z, acc.z);
        acc.w = fmaf(c, bv4.w, acc.w);
    }
    ((float4*)(ws + OFF_PART + (ch * 32 + l) * D_))[tid] = acc;
}

// ---- L5: WB reduce + split-K KV GEMM partials. grid 256 (l|sel|kc) x 512 ----
__global__ __launch_bounds__(512) void k_kv(
    const float* __restrict__ Wk, const float* __restrict__ Wv,
    float* __restrict__ ws)
{
    __shared__ float part[512];
    __shared__ float sx[128];
    int blk = blockIdx.x, tid = threadIdx.x;
    int l = blk & 31, sel = (blk >> 5) & 1, kc = blk >> 6;
    int p = tid & 127, c = tid >> 7;
    float s = 0.f;
    #pragma unroll
    for (int ch = c; ch < 32; ch += 4)
        s += ws[OFF_PART + (ch * 32 + l) * D_ + kc * 128 + p];
    part[tid] = s;
    __syncthreads();
    if (tid < 128) {
        float w = part[tid] + part[tid + 128] + part[tid + 256] + part[tid + 384];
        sx[tid] = w;
        if (sel == 0) ws[OFF_WB + l * D_ + kc * 128 + tid] = w;
    }
    __syncthreads();
    const float* W = sel ? Wv : Wk;
    float acc = 0.f;
    #pragma unroll 8
    for (int j = 0; j < 128; ++j) acc = fmaf(sx[j], W[(kc * 128 + j) * P_ + tid], acc);
    ws[OFF_AKVP + ((kc * 2 + sel) * 32 + l) * P_ + tid] = acc;
}

// ---- L6: logits (inline key partial-sum + bk) + softmax + EP (inline val
//          partial-sum + bv). grid 32 x 512 ----
__global__ __launch_bounds__(512) void k_attn(
    const float* __restrict__ bk, const float* __restrict__ bv,
    float* __restrict__ out_fa, float* __restrict__ ws)
{
    __shared__ __align__(16) float sq[512];
    __shared__ float slg[32];
    __shared__ float sfa[32];
    int l = blockIdx.x, tid = threadIdx.x, wv = tid >> 6, lane = tid & 63;
    sq[tid] = ws[OFF_QUERY + l * P_ + tid];
    __syncthreads();

    const float4* sq4 = (const float4*)sq;
    const float4* bk4 = (const float4*)bk;
    float4 q0 = sq4[lane * 2], q1 = sq4[lane * 2 + 1];
    float4 kb0 = bk4[lane * 2], kb1 = bk4[lane * 2 + 1];
    #pragma unroll
    for (int gi = 0; gi < 4; ++gi) {
        int g = wv * 4 + gi;
        float4 A = kb0, B = kb1;
        #pragma unroll
        for (int kc = 0; kc < 4; ++kc) {
            const float4* kr = (const float4*)(ws + OFF_AKVP + ((kc * 2) * 32 + g) * P_);
            float4 a = kr[lane * 2], b = kr[lane * 2 + 1];
            A.x += a.x; A.y += a.y; A.z += a.z; A.w += a.w;
            B.x += b.x; B.y += b.y; B.z += b.z; B.w += b.w;
        }
        float sdot = A.x * q0.x + A.y * q0.y + A.z * q0.z + A.w * q0.w
                   + B.x * q1.x + B.y * q1.y + B.z * q1.z + B.w * q1.w;
        sdot = wred64(sdot);
        if (lane == 0) slg[g] = sdot * SCALE;
    }
    __syncthreads();
    if (tid < 32) {
        float mx = -1e30f;
        for (int i = 0; i < 32; ++i) mx = fmaxf(mx, slg[i]);
        float Ssm = 0.f;
        for (int i = 0; i < 32; ++i) Ssm += expf(slg[i] - mx);
        float f = expf(slg[tid] - mx) / Ssm;
        sfa[tid] = f;
        out_fa[l * 32 + tid] = f;
    }
    __syncthreads();

    float bvp = bv[tid];
    float acc = 0.f;
    #pragma unroll 4
    for (int j = 0; j < 32; ++j) {
        float vs = ws[OFF_AKVP + ((0 * 2 + 1) * 32 + j) * P_ + tid]
                 + ws[OFF_AKVP + ((1 * 2 + 1) * 32 + j) * P_ + tid]
                 + ws[OFF_AKVP + ((2 * 2 + 1) * 32 + j) * P_ + tid]
                 + ws[OFF_AKVP + ((3 * 2 + 1) * 32 + j) * P_ + tid];
        acc = fmaf(sfa[j], vs + bvp, acc);
    }
    ws[OFF_EP2 + l * P_ + tid] = acc;
}

// ---- L7: split-K EP @ Wo partials. grid (32l, 8kc) x 512, 64-deep ----
__global__ __launch_bounds__(512) void k_evo(
    const float* __restrict__ Wo, float* __restrict__ ws)
{
    __shared__ float sx[64];
    int l = blockIdx.x, kc = blockIdx.y, tid = threadIdx.x;
    if (tid < 64) sx[tid] = ws[OFF_EP2 + l * P_ + kc * 64 + tid];
    __syncthreads();
    float acc = 0.f;
    #pragma unroll 8
    for (int j = 0; j < 64; ++j) acc = fmaf(sx[j], Wo[(kc * 64 + j) * D_ + tid], acc);
    ws[OFF_AEVOP + (kc * 32 + l) * D_ + tid] = acc;
}

// ---- L8: MLP1 with inline LN_in recompute. grid 512 (l|hc|kc) x 512 ----
__global__ __launch_bounds__(512) void k_mlp1(
    const float* __restrict__ Wa1, const float* __restrict__ bo,
    const float* __restrict__ g_in, const float* __restrict__ b_in,
    float* __restrict__ ws)
{
    __shared__ float sevo[512];
    __shared__ float buf[8];
    int blk = blockIdx.x, tid = threadIdx.x;
    int l = blk & 31, hc = (blk >> 5) & 3, kc = blk >> 7;
    float x = ws[OFF_WB + l * D_ + tid] + bo[tid];
    #pragma unroll
    for (int k2 = 0; k2 < 8; ++k2) x += ws[OFF_AEVOP + (k2 * 32 + l) * D_ + tid];
    float mean = bsum512(x, buf, tid) * (1.f / D_);
    float dx = x - mean;
    float var = bsum512(dx * dx, buf, tid) * (1.f / D_);
    sevo[tid] = dx * rsqrtf(var + EPS_) * g_in[tid] + b_in[tid];
    __syncthreads();
    int h = hc * 512 + tid;
    float acc = 0.f;
    #pragma unroll 8
    for (int j = 0; j < 128; ++j) acc = fmaf(sevo[kc * 128 + j], Wa1[(kc * 128 + j) * H_ + h], acc);
    ws[OFF_AH1P + (kc * 32 + l) * H_ + h] = acc;
}

// ---- L9: MLP2 split-K partials (relu+bias on the fly). grid 512 (l|kc) x 512 ----
__global__ __launch_bounds__(512) void k_mlp2(
    const float* __restrict__ Wa2, const float* __restrict__ ba1,
    float* __restrict__ ws)
{
    __shared__ float sh[128];
    int blk = blockIdx.x, tid = threadIdx.x;
    int l = blk & 31, kc = blk >> 5;   // kc 0..15
    if (tid < 128) {
        int h = kc * 128 + tid;
        float a = ba1[h];
        #pragma unroll
        for (int k4 = 0; k4 < 4; ++k4) a += ws[OFF_AH1P + (k4 * 32 + l) * H_ + h];
        sh[tid] = fmaxf(a, 0.f);
    }
    __syncthreads();
    float acc = 0.f;
    #pragma unroll 8
    for (int j = 0; j < 128; ++j) acc = fmaf(sh[j], Wa2[(kc * 128 + j) * D_ + tid], acc);
    ws[OFF_AOUTP + (kc * 32 + l) * D_ + tid] = acc;
}

// ---- L10: LN_out with inline LN_in recompute -> aligned. grid 32 x 512 ----
__global__ __launch_bounds__(512) void k_lnout(
    const float* __restrict__ bo, const float* __restrict__ g_in,
    const float* __restrict__ b_in, const float* __restrict__ ba2,
    const float* __restrict__ g_out, const float* __restrict__ b_out,
    float* __restrict__ out_al, float* __restrict__ ws)
{
    __shared__ float buf[8];
    int l = blockIdx.x, tid = threadIdx.x;
    // recompute EVOLVED[l,tid] (identical arithmetic to k_mlp1)
    float x = ws[OFF_WB + l * D_ + tid] + bo[tid];
    #pragma unroll
    for (int k2 = 0; k2 < 8; ++k2) x += ws[OFF_AEVOP + (k2 * 32 + l) * D_ + tid];
    float mean = bsum512(x, buf, tid) * (1.f / D_);
    float dx = x - mean;
    float var = bsum512(dx * dx, buf, tid) * (1.f / D_);
    float evo = dx * rsqrtf(var + EPS_) * g_in[tid] + b_in[tid];
    // LN_out
    float x2 = evo + ba2[tid];
    #pragma unroll
    for (int kc = 0; kc < 16; ++kc) x2 += ws[OFF_AOUTP + (kc * 32 + l) * D_ + tid];
    float mean2 = bsum512(x2, buf, tid) * (1.f / D_);
    float dx2 = x2 - mean2;
    float var2 = bsum512(dx2 * dx2, buf, tid) * (1.f / D_);
    out_al[l * D_ + tid] = dx2 * rsqrtf(var2 + EPS_) * g_out[tid] + b_out[tid];
}

// ---- L11: aligned_prompts broadcast, 64 MB write. grid 4096 x 256 ----
__global__ __launch_bounds__(256) void k_bcast(float* __restrict__ out) {
    const float4* src = (const float4*)out;       // 4096 float4
    float4* dst = (float4*)(out + OFFO_AP);
    int idx = blockIdx.x * 256 + threadIdx.x;
    #pragma unroll
    for (int k = 0; k < 4; ++k) {
        int v = idx + k * 1048576;
        dst[v] = src[v & 4095];
    }
}

extern "C" void kernel_launch(void* const* d_in, const int* in_sizes, int n_in,
                              void* d_out, int out_size, void* d_ws, size_t ws_size,
                              hipStream_t stream) {
    const float* base = (const float*)d_in[0];
    const float* np   = (const float*)d_in[1];
    const float* te   = (const float*)d_in[2];
    const float* Wt   = (const float*)d_in[3];
    const float* bt   = (const float*)d_in[4];
    const float* Wq   = (const float*)d_in[5];
    const float* bq   = (const float*)d_in[6];
    const float* Wk   = (const float*)d_in[7];
    const float* bk   = (const float*)d_in[8];
    const float* Wv   = (const float*)d_in[9];
    const float* bv   = (const float*)d_in[10];
    const float* Wo   = (const float*)d_in[11];
    const float* bo   = (const float*)d_in[12];
    const float* Wa1  = (const float*)d_in[13];
    const float* ba1  = (const float*)d_in[14];
    const float* Wa2  = (const float*)d_in[15];
    const float* ba2  = (const float*)d_in[16];
    const float* g_in = (const float*)d_in[17];
    const float* b_in = (const float*)d_in[18];
    const float* g_out= (const float*)d_in[19];
    const float* b_out= (const float*)d_in[20];
    float* out = (float*)d_out;
    float* ws = out + OFFO_AP;

    hipLaunchKernelGGL(k_aq_sb, dim3(1332),    dim3(512), 0, stream,
                       base, np, te, Wq, Wt, Wk, Wv, Wo, Wa1, Wa2, ws);
    hipLaunchKernelGGL(k_prep,  dim3(64),      dim3(512), 0, stream, Wk, bk, bq, bt, ws);
    hipLaunchKernelGGL(k_uv,    dim3(1024),    dim3(512), 0, stream, ws);
    hipLaunchKernelGGL(k_part,  dim3(32, 32),  dim3(128), 0, stream, base, out + OFFO_TW, ws);
    hipLaunchKernelGGL(k_kv,    dim3(256),     dim3(512), 0, stream, Wk, Wv, ws);
    hipLaunchKernelGGL(k_attn,  dim3(32),      dim3(512), 0, stream, bk, bv, out + OFFO_FA, ws);
    hipLaunchKernelGGL(k_evo,   dim3(32, 8),   dim3(512), 0, stream, Wo, ws);
    hipLaunchKernelGGL(k_mlp1,  dim3(512),     dim3(512), 0, stream, Wa1, bo, g_in, b_in, ws);
    hipLaunchKernelGGL(k_mlp2,  dim3(512),     dim3(512), 0, stream, Wa2, ba1, ws);
    hipLaunchKernelGGL(k_lnout, dim3(32),      dim3(512), 0, stream,
                       bo, g_in, b_in, ba2, g_out, b_out, out + OFFO_AL, ws);
    hipLaunchKernelGGL(k_bcast, dim3(4096),    dim3(256), 0, stream, out);
}

// Round 6
// 256.941 us; speedup vs baseline: 2.5641x; 1.0057x over previous
//
#include <hip/hip_runtime.h>

// RainbowEvolution T=1024 L=32 D=512 P=512 H=2048. fp32 in / fp32 out.
// R11: R10 with the two remaining narrow-grid latency chains widened:
//  - k_attn (32 blk) -> k_logits (256 blk, wave-per-dot) + k_evoEP (256 blk:
//    redundant 32-wide softmax + EP slice + 64-deep Wo GEMM). R8b measured
//    this kernel shape (32-blk deep-loop) at 4-5x roofline; widening fixes.
//  - k_lnout + k_bcast fused -> k_lnbcast (1024 blk; each recomputes the two
//    LNs for its l-row from hot partials, then writes 32 t-copies float4).
//  - ALL scratch moved to d_ws (harness workspace) — removes the AP-region
//    read-after-overwrite hazard and frees the broadcast fusion.
// Split-K partials everywhere, no atomics, no zero pass. L1 prewarms weights
// into L3 alongside the base scan. 10 launches.

static constexpr int T_ = 1024, L_ = 32, D_ = 512, P_ = 512, H_ = 2048;
static constexpr float SCALE = 0.04419417382415922f; // 1/sqrt(512)
static constexpr float EPS_ = 1e-5f;

// out layout (fp32 offsets): aligned, aligned_prompts, task_weights, feature_attn
static constexpr int OFFO_AL = 0;
static constexpr int OFFO_AP = 16384;
static constexpr int OFFO_TW = 16384 + 16777216;   // 16793600
static constexpr int OFFO_FA = OFFO_TW + 1024;     // 16794624

// scratch (fp32 offsets into ws = (float*)d_ws)
static constexpr int OFF_SB      = 0;        // [1024][512] sum_l base
static constexpr int OFF_AQP     = 524288;   // [4kc][33][512] query|tv partials
static constexpr int OFF_QUERY   = 591872;   // [32][512]
static constexpr int OFF_WKTV    = 608256;   // [512]
static constexpr int OFF_WKPQ    = 608768;   // [512]
static constexpr int OFF_SC      = 609280;   // [64] scalars: bkt, bkq
static constexpr int OFF_U       = 609344;   // [1024]
static constexpr int OFF_V       = 610368;   // [1024]
static constexpr int OFF_PART    = 611392;   // [32ch][32l][512]
static constexpr int OFF_WB      = 1135680;  // [32][512]
static constexpr int OFF_AKVP    = 1152064;  // [4kc][2sel][32][512]
static constexpr int OFF_LG      = 1283136;  // [32][32] raw logits
static constexpr int OFF_AH1P    = 1284160;  // [4kc][32][2048]
static constexpr int OFF_AOUTP   = 1546304;  // [16kc][32][512]
static constexpr int OFF_AEVOP   = 1808448;  // [8kc][32][512]
static constexpr int OFF_DUMMY   = 1939520;  // [176*512] prewarm sink

// ---- reductions ----
__device__ __forceinline__ float wred64(float v) {
    #pragma unroll
    for (int off = 32; off > 0; off >>= 1) v += __shfl_down(v, off, 64);
    return v;
}
__device__ __forceinline__ float wmax64(float v) {
    #pragma unroll
    for (int off = 32; off > 0; off >>= 1) v = fmaxf(v, __shfl_down(v, off, 64));
    return v;
}
__device__ __forceinline__ float bsum512(float v, float* buf, int tid) {
    v = wred64(v);
    __syncthreads();
    if ((tid & 63) == 0) buf[tid >> 6] = v;
    __syncthreads();
    float s = 0.f;
    #pragma unroll
    for (int i = 0; i < 8; ++i) s += buf[i];
    return s;
}
__device__ __forceinline__ float bsum128(float v, float* buf, int tid) {
    v = wred64(v);
    __syncthreads();
    if ((tid & 63) == 0) buf[tid >> 6] = v;
    __syncthreads();
    return buf[0] + buf[1];
}
__device__ __forceinline__ float bmax128(float v, float* buf, int tid) {
    v = wmax64(v);
    __syncthreads();
    if ((tid & 63) == 0) buf[tid >> 6] = v;
    __syncthreads();
    return fmaxf(buf[0], buf[1]);
}

// ---- L1: prewarm weights (0..175) + AQ partial GEMM (176..307) + SB scan ----
__global__ __launch_bounds__(512) void k_aq_sb(
    const float* __restrict__ base, const float* __restrict__ np_,
    const float* __restrict__ te, const float* __restrict__ Wq,
    const float* __restrict__ Wt, const float* __restrict__ Wk,
    const float* __restrict__ Wv, const float* __restrict__ Wo,
    const float* __restrict__ Wa1, const float* __restrict__ Wa2,
    float* __restrict__ ws)
{
    __shared__ __align__(16) float4 smem4[512];   // 8 KB
    int blk = blockIdx.x, tid = threadIdx.x;
    if (blk < 176) {
        const float* src;
        int pw = blk;
        if (pw < 16)       src = Wo  + pw * 16384;
        else if (pw < 80)  src = Wa1 + (pw - 16) * 16384;
        else if (pw < 144) src = Wa2 + (pw - 80) * 16384;
        else if (pw < 160) src = Wk  + (pw - 144) * 16384;
        else               src = Wv  + (pw - 160) * 16384;
        const float4* s4 = (const float4*)src;
        float4 acc = make_float4(0.f, 0.f, 0.f, 0.f);
        #pragma unroll
        for (int i = 0; i < 8; ++i) {
            float4 v = s4[i * 512 + tid];
            acc.x += v.x; acc.y += v.y; acc.z += v.z; acc.w += v.w;
        }
        ws[OFF_DUMMY + pw * 512 + tid] = acc.x + acc.y + acc.z + acc.w;
    } else if (blk < 308) {
        float* sx = (float*)smem4;                // 128 floats
        int b = (blk - 176) % 33, kc = (blk - 176) / 33;
        const float* x = (b < 32) ? (np_ + b * D_) : te;
        const float* W = (b < 32) ? Wq : Wt;
        if (tid < 128) sx[tid] = x[kc * 128 + tid];
        __syncthreads();
        float acc = 0.f;
        #pragma unroll 8
        for (int j = 0; j < 128; ++j) acc = fmaf(sx[j], W[(kc * 128 + j) * P_ + tid], acc);
        ws[OFF_AQP + (kc * 33 + b) * P_ + tid] = acc;
    } else {
        int t = blk - 308;
        const float4* bp = (const float4*)(base + (size_t)t * (L_ * D_));
        int d4 = tid & 127, lq = tid >> 7;
        float4 acc = make_float4(0.f, 0.f, 0.f, 0.f);
        #pragma unroll
        for (int i = 0; i < 8; ++i) {
            int l = i * 4 + lq;
            float4 v = bp[l * 128 + d4];
            acc.x += v.x; acc.y += v.y; acc.z += v.z; acc.w += v.w;
        }
        smem4[tid] = acc;
        __syncthreads();
        if (tid < 128) {
            float4 a = smem4[tid], b2 = smem4[tid + 128];
            float4 c = smem4[tid + 256], d2 = smem4[tid + 384];
            float4 r;
            r.x = a.x + b2.x + c.x + d2.x;
            r.y = a.y + b2.y + c.y + d2.y;
            r.z = a.z + b2.z + c.z + d2.z;
            r.w = a.w + b2.w + c.w + d2.w;
            ((float4*)(ws + OFF_SB + t * D_))[tid] = r;
        }
    }
}

// ---- L2: QUERY rows, TV/PQ (redundant), WKTV/WKPQ, bkt/bkq. grid 64 x 512 ----
__global__ __launch_bounds__(512) void k_prep(
    const float* __restrict__ Wk, const float* __restrict__ bk,
    const float* __restrict__ bq, const float* __restrict__ bt,
    float* __restrict__ ws)
{
    __shared__ __align__(16) float stv[512];
    __shared__ __align__(16) float spq[512];
    __shared__ float buf[8];
    int blk = blockIdx.x, tid = threadIdx.x;

    float a = 0.f;
    #pragma unroll
    for (int kc = 0; kc < 4; ++kc) a += ws[OFF_AQP + (kc * 33 + 32) * P_ + tid];
    stv[tid] = tanhf(a + bt[tid]);

    float b = 0.f;
    #pragma unroll 4
    for (int kc = 0; kc < 4; ++kc)
        for (int l = 0; l < 32; ++l) b += ws[OFF_AQP + (kc * 33 + l) * P_ + tid];
    spq[tid] = b * (1.f / 32.f) + bq[tid];

    if (blk < 32) {
        float q = bq[tid];
        #pragma unroll
        for (int kc = 0; kc < 4; ++kc) q += ws[OFF_AQP + (kc * 33 + blk) * P_ + tid];
        ws[OFF_QUERY + blk * P_ + tid] = q;
    }
    __syncthreads();

    int wv = tid >> 6, lane = tid & 63;
    int d = blk * 8 + wv;
    const float4* row = (const float4*)(Wk + d * P_);
    const float4* tv4 = (const float4*)stv;
    const float4* pq4 = (const float4*)spq;
    float4 r0 = row[lane * 2], r1 = row[lane * 2 + 1];
    float4 t0 = tv4[lane * 2], t1 = tv4[lane * 2 + 1];
    float4 q0 = pq4[lane * 2], q1 = pq4[lane * 2 + 1];
    float pa = r0.x * t0.x + r0.y * t0.y + r0.z * t0.z + r0.w * t0.w
             + r1.x * t1.x + r1.y * t1.y + r1.z * t1.z + r1.w * t1.w;
    float pb = r0.x * q0.x + r0.y * q0.y + r0.z * q0.z + r0.w * q0.w
             + r1.x * q1.x + r1.y * q1.y + r1.z * q1.z + r1.w * q1.w;
    pa = wred64(pa); pb = wred64(pb);
    if (lane == 0) { ws[OFF_WKTV + d] = pa; ws[OFF_WKPQ + d] = pb; }

    if (blk == 63) {
        float bkf = bk[tid];
        float s1 = bsum512(bkf * stv[tid], buf, tid);
        float s2 = bsum512(bkf * spq[tid], buf, tid);
        if (tid == 0) { ws[OFF_SC] = s1; ws[OFF_SC + 1] = s2; }
    }
}

// ---- L3: U[t], V[t]. grid 1024 x 512 ----
__global__ __launch_bounds__(512) void k_uv(float* __restrict__ ws)
{
    __shared__ float buf[8];
    int t = blockIdx.x, tid = threadIdx.x;
    float sb = ws[OFF_SB + t * D_ + tid];
    float a = bsum512(sb * ws[OFF_WKTV + tid], buf, tid);
    float b = bsum512(sb * ws[OFF_WKPQ + tid], buf, tid);
    if (tid == 0) {
        ws[OFF_U + t] = a * (1.f / L_);
        ws[OFF_V + t] = b * (1.f / L_);
    }
}

// ---- L4: redundant task-softmax + weighted pooling PART. grid(32l,32ch) x128 ----
__global__ __launch_bounds__(128) void k_part(
    const float* __restrict__ base, float* __restrict__ out_tw,
    float* __restrict__ ws)
{
    __shared__ float sC[1024];
    __shared__ float rbuf[2];
    int l = blockIdx.x, ch = blockIdx.y, tid = threadIdx.x;
    float bkt = ws[OFF_SC], bkq = ws[OFF_SC + 1];

    float u[8], v[8], s1[8], tw1[8], tw[8];
    #pragma unroll
    for (int i = 0; i < 8; ++i) {
        int t = i * 128 + tid;
        u[i] = ws[OFF_U + t];
        v[i] = ws[OFF_V + t];
    }
    float lmax = -1e30f;
    #pragma unroll
    for (int i = 0; i < 8; ++i) { s1[i] = (u[i] + bkt) * SCALE; lmax = fmaxf(lmax, s1[i]); }
    float gmax = bmax128(lmax, rbuf, tid);
    float ls = 0.f;
    #pragma unroll
    for (int i = 0; i < 8; ++i) { s1[i] = expf(s1[i] - gmax); ls += s1[i]; }
    float gs = bsum128(ls, rbuf, tid);
    #pragma unroll
    for (int i = 0; i < 8; ++i) tw1[i] = s1[i] / gs;
    lmax = -1e30f;
    #pragma unroll
    for (int i = 0; i < 8; ++i) {
        s1[i] = ((1.f + tw1[i]) * v[i] + bkq) * SCALE;
        lmax = fmaxf(lmax, s1[i]);
    }
    gmax = bmax128(lmax, rbuf, tid);
    ls = 0.f;
    #pragma unroll
    for (int i = 0; i < 8; ++i) { s1[i] = expf(s1[i] - gmax); ls += s1[i]; }
    gs = bsum128(ls, rbuf, tid);
    float lsum = 0.f;
    #pragma unroll
    for (int i = 0; i < 8; ++i) {
        tw[i] = 0.5f * tw1[i] + 0.5f * (s1[i] / gs);
        lsum += tw[i];
    }
    float S = bsum128(lsum, rbuf, tid);
    S = fmaxf(S, 1e-6f);
    #pragma unroll
    for (int i = 0; i < 8; ++i) {
        int t = i * 128 + tid;
        float twn = tw[i] / S;
        sC[t] = twn * (1.f + tw1[i]);
        if (l == 0 && ch == 0) out_tw[t] = twn;
    }
    __syncthreads();

    float4 acc = make_float4(0.f, 0.f, 0.f, 0.f);
    for (int i = 0; i < 32; ++i) {
        int t = ch * 32 + i;
        float c = sC[t];
        float4 bv4 = ((const float4*)(base + ((size_t)t * L_ + l) * D_))[tid];
        acc.x = fmaf(c, bv4.x, acc.x);
        acc.y = fmaf(c, bv4.y, acc.y);
        acc.z = fmaf(c, bv4.z, acc.z);
        acc.w = fmaf(c, bv4.w, acc.w);
    }
    ((float4*)(ws + OFF_PART + (ch * 32 + l) * D_))[tid] = acc;
}

// ---- L5: WB reduce + split-K KV GEMM partials. grid 256 (l|sel|kc) x 512 ----
__global__ __launch_bounds__(512) void k_kv(
    const float* __restrict__ Wk, const float* __restrict__ Wv,
    float* __restrict__ ws)
{
    __shared__ float part[512];
    __shared__ float sx[128];
    int blk = blockIdx.x, tid = threadIdx.x;
    int l = blk & 31, sel = (blk >> 5) & 1, kc = blk >> 6;
    int p = tid & 127, c = tid >> 7;
    float s = 0.f;
    #pragma unroll
    for (int ch = c; ch < 32; ch += 4)
        s += ws[OFF_PART + (ch * 32 + l) * D_ + kc * 128 + p];
    part[tid] = s;
    __syncthreads();
    if (tid < 128) {
        float w = part[tid] + part[tid + 128] + part[tid + 256] + part[tid + 384];
        sx[tid] = w;
        if (sel == 0) ws[OFF_WB + l * D_ + kc * 128 + tid] = w;
    }
    __syncthreads();
    const float* W = sel ? Wv : Wk;
    float acc = 0.f;
    #pragma unroll 8
    for (int j = 0; j < 128; ++j) acc = fmaf(sx[j], W[(kc * 128 + j) * P_ + tid], acc);
    ws[OFF_AKVP + ((kc * 2 + sel) * 32 + l) * P_ + tid] = acc;
}

// ---- L6: raw logits, wave-per-(l,g). grid (32l, 8gc) x 512 ----
__global__ __launch_bounds__(512) void k_logits(
    const float* __restrict__ bk, float* __restrict__ ws)
{
    __shared__ __align__(16) float sq[512];
    int l = blockIdx.x, gc = blockIdx.y, tid = threadIdx.x;
    int wv = tid >> 6, lane = tid & 63;
    sq[tid] = ws[OFF_QUERY + l * P_ + tid];
    __syncthreads();
    const float4* sq4 = (const float4*)sq;
    const float4* bk4 = (const float4*)bk;
    float4 q0 = sq4[lane * 2], q1 = sq4[lane * 2 + 1];
    float4 A = bk4[lane * 2], B = bk4[lane * 2 + 1];
    int g = gc * 4 + wv;
    #pragma unroll
    for (int kc = 0; kc < 4; ++kc) {
        const float4* kr = (const float4*)(ws + OFF_AKVP + ((kc * 2) * 32 + g) * P_);
        float4 a = kr[lane * 2], b = kr[lane * 2 + 1];
        A.x += a.x; A.y += a.y; A.z += a.z; A.w += a.w;
        B.x += b.x; B.y += b.y; B.z += b.z; B.w += b.w;
    }
    float sdot = A.x * q0.x + A.y * q0.y + A.z * q0.z + A.w * q0.w
               + B.x * q1.x + B.y * q1.y + B.z * q1.z + B.w * q1.w;
    sdot = wred64(sdot);
    if (lane == 0) ws[OFF_LG + l * 32 + g] = sdot * SCALE;
}

// ---- L7: softmax (redundant) + EP slice + 64-deep Wo GEMM.
//          grid (32l, 8kc) x 512 ----
__global__ __launch_bounds__(512) void k_evoEP(
    const float* __restrict__ bv, const float* __restrict__ Wo,
    float* __restrict__ out_fa, float* __restrict__ ws)
{
    __shared__ float slg[32];
    __shared__ float sfa[32];
    __shared__ float pe[8][64];
    __shared__ float sx[64];
    int l = blockIdx.x, kc = blockIdx.y, tid = threadIdx.x;
    if (tid < 32) slg[tid] = ws[OFF_LG + l * 32 + tid];
    __syncthreads();
    if (tid < 32) {
        float mx = -1e30f;
        for (int i = 0; i < 32; ++i) mx = fmaxf(mx, slg[i]);
        float S = 0.f;
        for (int i = 0; i < 32; ++i) S += expf(slg[i] - mx);
        float f = expf(slg[tid] - mx) / S;
        sfa[tid] = f;
        if (kc == 0) out_fa[l * 32 + tid] = f;
    }
    __syncthreads();

    // EP slice: p in [kc*64, kc*64+64); 8 j-groups of 4
    int p = tid & 63, jg = tid >> 6;
    float bvp = bv[kc * 64 + p];
    float acc = 0.f;
    #pragma unroll
    for (int jj = 0; jj < 4; ++jj) {
        int j = jg * 4 + jj;
        float vs = ws[OFF_AKVP + (1 * 32 + j) * P_ + kc * 64 + p]
                 + ws[OFF_AKVP + (3 * 32 + j) * P_ + kc * 64 + p]
                 + ws[OFF_AKVP + (5 * 32 + j) * P_ + kc * 64 + p]
                 + ws[OFF_AKVP + (7 * 32 + j) * P_ + kc * 64 + p];
        acc = fmaf(sfa[j], vs + bvp, acc);
    }
    pe[jg][p] = acc;
    __syncthreads();
    if (tid < 64) {
        float s = 0.f;
        #pragma unroll
        for (int i = 0; i < 8; ++i) s += pe[i][tid];
        sx[tid] = s;
    }
    __syncthreads();

    float a2 = 0.f;
    #pragma unroll 8
    for (int j = 0; j < 64; ++j) a2 = fmaf(sx[j], Wo[(kc * 64 + j) * D_ + tid], a2);
    ws[OFF_AEVOP + (kc * 32 + l) * D_ + tid] = a2;
}

// ---- L8: MLP1 with inline LN_in recompute. grid 512 (l|hc|kc) x 512 ----
__global__ __launch_bounds__(512) void k_mlp1(
    const float* __restrict__ Wa1, const float* __restrict__ bo,
    const float* __restrict__ g_in, const float* __restrict__ b_in,
    float* __restrict__ ws)
{
    __shared__ float sevo[512];
    __shared__ float buf[8];
    int blk = blockIdx.x, tid = threadIdx.x;
    int l = blk & 31, hc = (blk >> 5) & 3, kc = blk >> 7;
    float x = ws[OFF_WB + l * D_ + tid] + bo[tid];
    #pragma unroll
    for (int k2 = 0; k2 < 8; ++k2) x += ws[OFF_AEVOP + (k2 * 32 + l) * D_ + tid];
    float mean = bsum512(x, buf, tid) * (1.f / D_);
    float dx = x - mean;
    float var = bsum512(dx * dx, buf, tid) * (1.f / D_);
    sevo[tid] = dx * rsqrtf(var + EPS_) * g_in[tid] + b_in[tid];
    __syncthreads();
    int h = hc * 512 + tid;
    float acc = 0.f;
    #pragma unroll 8
    for (int j = 0; j < 128; ++j) acc = fmaf(sevo[kc * 128 + j], Wa1[(kc * 128 + j) * H_ + h], acc);
    ws[OFF_AH1P + (kc * 32 + l) * H_ + h] = acc;
}

// ---- L9: MLP2 split-K partials (relu+bias on the fly). grid 512 (l|kc) x 512 ----
__global__ __launch_bounds__(512) void k_mlp2(
    const float* __restrict__ Wa2, const float* __restrict__ ba1,
    float* __restrict__ ws)
{
    __shared__ float sh[128];
    int blk = blockIdx.x, tid = threadIdx.x;
    int l = blk & 31, kc = blk >> 5;   // kc 0..15
    if (tid < 128) {
        int h = kc * 128 + tid;
        float a = ba1[h];
        #pragma unroll
        for (int k4 = 0; k4 < 4; ++k4) a += ws[OFF_AH1P + (k4 * 32 + l) * H_ + h];
        sh[tid] = fmaxf(a, 0.f);
    }
    __syncthreads();
    float acc = 0.f;
    #pragma unroll 8
    for (int j = 0; j < 128; ++j) acc = fmaf(sh[j], Wa2[(kc * 128 + j) * D_ + tid], acc);
    ws[OFF_AOUTP + (kc * 32 + l) * D_ + tid] = acc;
}

// ---- L10: LN_in + LN_out recompute + aligned + broadcast.
//           grid (32l, 32tc) x 512 ----
__global__ __launch_bounds__(512) void k_lnbcast(
    const float* __restrict__ bo, const float* __restrict__ g_in,
    const float* __restrict__ b_in, const float* __restrict__ ba2,
    const float* __restrict__ g_out, const float* __restrict__ b_out,
    float* __restrict__ out, float* __restrict__ ws)
{
    __shared__ float buf[8];
    __shared__ __align__(16) float sal[512];
    int l = blockIdx.x, tc = blockIdx.y, tid = threadIdx.x;
    // EVOLVED recompute (identical arithmetic to k_mlp1)
    float x = ws[OFF_WB + l * D_ + tid] + bo[tid];
    #pragma unroll
    for (int k2 = 0; k2 < 8; ++k2) x += ws[OFF_AEVOP + (k2 * 32 + l) * D_ + tid];
    float mean = bsum512(x, buf, tid) * (1.f / D_);
    float dx = x - mean;
    float var = bsum512(dx * dx, buf, tid) * (1.f / D_);
    float evo = dx * rsqrtf(var + EPS_) * g_in[tid] + b_in[tid];
    // LN_out
    float x2 = evo + ba2[tid];
    #pragma unroll
    for (int kc = 0; kc < 16; ++kc) x2 += ws[OFF_AOUTP + (kc * 32 + l) * D_ + tid];
    float mean2 = bsum512(x2, buf, tid) * (1.f / D_);
    float dx2 = x2 - mean2;
    float var2 = bsum512(dx2 * dx2, buf, tid) * (1.f / D_);
    float a = dx2 * rsqrtf(var2 + EPS_) * g_out[tid] + b_out[tid];
    if (tc == 0) out[OFFO_AL + l * D_ + tid] = a;
    sal[tid] = a;
    __syncthreads();
    // broadcast 32 t-rows, float4 stores (4 rows per pass)
    float4 v = ((const float4*)sal)[tid & 127];
    int row = tid >> 7;
    #pragma unroll
    for (int pass = 0; pass < 8; ++pass) {
        int t = tc * 32 + pass * 4 + row;
        ((float4*)(out + OFFO_AP + (size_t)t * (L_ * D_) + l * D_))[tid & 127] = v;
    }
}

extern "C" void kernel_launch(void* const* d_in, const int* in_sizes, int n_in,
                              void* d_out, int out_size, void* d_ws, size_t ws_size,
                              hipStream_t stream) {
    const float* base = (const float*)d_in[0];
    const float* np   = (const float*)d_in[1];
    const float* te   = (const float*)d_in[2];
    const float* Wt   = (const float*)d_in[3];
    const float* bt   = (const float*)d_in[4];
    const float* Wq   = (const float*)d_in[5];
    const float* bq   = (const float*)d_in[6];
    const float* Wk   = (const float*)d_in[7];
    const float* bk   = (const float*)d_in[8];
    const float* Wv   = (const float*)d_in[9];
    const float* bv   = (const float*)d_in[10];
    const float* Wo   = (const float*)d_in[11];
    const float* bo   = (const float*)d_in[12];
    const float* Wa1  = (const float*)d_in[13];
    const float* ba1  = (const float*)d_in[14];
    const float* Wa2  = (const float*)d_in[15];
    const float* ba2  = (const float*)d_in[16];
    const float* g_in = (const float*)d_in[17];
    const float* b_in = (const float*)d_in[18];
    const float* g_out= (const float*)d_in[19];
    const float* b_out= (const float*)d_in[20];
    float* out = (float*)d_out;
    float* ws = (float*)d_ws;

    hipLaunchKernelGGL(k_aq_sb,   dim3(1332),   dim3(512), 0, stream,
                       base, np, te, Wq, Wt, Wk, Wv, Wo, Wa1, Wa2, ws);
    hipLaunchKernelGGL(k_prep,    dim3(64),     dim3(512), 0, stream, Wk, bk, bq, bt, ws);
    hipLaunchKernelGGL(k_uv,      dim3(1024),   dim3(512), 0, stream, ws);
    hipLaunchKernelGGL(k_part,    dim3(32, 32), dim3(128), 0, stream, base, out + OFFO_TW, ws);
    hipLaunchKernelGGL(k_kv,      dim3(256),    dim3(512), 0, stream, Wk, Wv, ws);
    hipLaunchKernelGGL(k_logits,  dim3(32, 8),  dim3(512), 0, stream, bk, ws);
    hipLaunchKernelGGL(k_evoEP,   dim3(32, 8),  dim3(512), 0, stream, bv, Wo, out + OFFO_FA, ws);
    hipLaunchKernelGGL(k_mlp1,    dim3(512),    dim3(512), 0, stream, Wa1, bo, g_in, b_in, ws);
    hipLaunchKernelGGL(k_mlp2,    dim3(512),    dim3(512), 0, stream, Wa2, ba1, ws);
    hipLaunchKernelGGL(k_lnbcast, dim3(32, 32), dim3(512), 0, stream,
                       bo, g_in, b_in, ba2, g_out, b_out, out, ws);
}

// Round 7
// 235.958 us; speedup vs baseline: 2.7921x; 1.0889x over previous
//
#include <hip/hip_runtime.h>

// RainbowEvolution T=1024 L=32 D=512 P=512 H=2048. fp32 in / fp32 out.
// R12: calibration across R7-R11 shows ~165-190us of fixed harness overhead
// (268MB workspace re-poison fills) per iteration; our kernels are ~90us.
// Changes vs R11:
//  - SB eliminated: k_scanuv computes U[t],V[t] inline during the base scan
//    (head serialized: k_aq+prewarm -> k_prep -> k_scanuv).
//  - MLP GEMMs 4-l-batched (128 blocks, weight reuse x4 in registers;
//    L2 traffic 128MB -> 32MB each).
//  - EVOLVED materialized once (k_lnin); no double-LN recompute in consumers.
// Split-K partials, no atomics, no zero pass. 11 launches.

static constexpr int T_ = 1024, L_ = 32, D_ = 512, P_ = 512, H_ = 2048;
static constexpr float SCALE = 0.04419417382415922f; // 1/sqrt(512)
static constexpr float EPS_ = 1e-5f;

// out layout (fp32 offsets): aligned, aligned_prompts, task_weights, feature_attn
static constexpr int OFFO_AL = 0;
static constexpr int OFFO_AP = 16384;
static constexpr int OFFO_TW = 16384 + 16777216;   // 16793600
static constexpr int OFFO_FA = OFFO_TW + 1024;     // 16794624

// scratch (fp32 offsets into ws = (float*)d_ws)
static constexpr int OFF_AQP     = 0;        // [4kc][33][512]
static constexpr int OFF_QUERY   = 67584;    // [32][512]
static constexpr int OFF_WKTV    = 83968;    // [512]
static constexpr int OFF_WKPQ    = 84480;    // [512]
static constexpr int OFF_SC      = 84992;    // [64] scalars: bkt, bkq
static constexpr int OFF_U       = 85056;    // [1024]
static constexpr int OFF_V       = 86080;    // [1024]
static constexpr int OFF_PART    = 87104;    // [32ch][32l][512]
static constexpr int OFF_WB      = 611392;   // [32][512]
static constexpr int OFF_AKVP    = 627776;   // [4kc][2sel][32][512]
static constexpr int OFF_LG      = 758848;   // [32][32]
static constexpr int OFF_AEVOP   = 759872;   // [8kc][32][512]
static constexpr int OFF_EVOLVED = 890944;   // [32][512]
static constexpr int OFF_AH1P    = 907328;   // [4kc][32][2048]
static constexpr int OFF_AOUTP   = 1169472;  // [16kc][32][512]
static constexpr int OFF_DUMMY   = 1431616;  // [160*512] prewarm sink

// ---- reductions ----
__device__ __forceinline__ float wred64(float v) {
    #pragma unroll
    for (int off = 32; off > 0; off >>= 1) v += __shfl_down(v, off, 64);
    return v;
}
__device__ __forceinline__ float wmax64(float v) {
    #pragma unroll
    for (int off = 32; off > 0; off >>= 1) v = fmaxf(v, __shfl_down(v, off, 64));
    return v;
}
__device__ __forceinline__ float bsum512(float v, float* buf, int tid) {
    v = wred64(v);
    __syncthreads();
    if ((tid & 63) == 0) buf[tid >> 6] = v;
    __syncthreads();
    float s = 0.f;
    #pragma unroll
    for (int i = 0; i < 8; ++i) s += buf[i];
    return s;
}
__device__ __forceinline__ float bsum128(float v, float* buf, int tid) {
    v = wred64(v);
    __syncthreads();
    if ((tid & 63) == 0) buf[tid >> 6] = v;
    __syncthreads();
    return buf[0] + buf[1];
}
__device__ __forceinline__ float bmax128(float v, float* buf, int tid) {
    v = wmax64(v);
    __syncthreads();
    if ((tid & 63) == 0) buf[tid >> 6] = v;
    __syncthreads();
    return fmaxf(buf[0], buf[1]);
}

// ---- L1: AQ partials (0..131) + prewarm Wo/Wa1/Wa2/Wv (132..291) ----
__global__ __launch_bounds__(512) void k_aq(
    const float* __restrict__ np_, const float* __restrict__ te,
    const float* __restrict__ Wq, const float* __restrict__ Wt,
    const float* __restrict__ Wv, const float* __restrict__ Wo,
    const float* __restrict__ Wa1, const float* __restrict__ Wa2,
    float* __restrict__ ws)
{
    __shared__ float sx[128];
    int blk = blockIdx.x, tid = threadIdx.x;
    if (blk < 132) {
        int b = blk % 33, kc = blk / 33;
        const float* x = (b < 32) ? (np_ + b * D_) : te;
        const float* W = (b < 32) ? Wq : Wt;
        if (tid < 128) sx[tid] = x[kc * 128 + tid];
        __syncthreads();
        float acc = 0.f;
        #pragma unroll 8
        for (int j = 0; j < 128; ++j) acc = fmaf(sx[j], W[(kc * 128 + j) * P_ + tid], acc);
        ws[OFF_AQP + (kc * 33 + b) * P_ + tid] = acc;
    } else {
        int pw = blk - 132;     // 0..159: Wo 0-15, Wa1 16-79, Wa2 80-143, Wv 144-159
        const float* src;
        if (pw < 16)       src = Wo  + pw * 16384;
        else if (pw < 80)  src = Wa1 + (pw - 16) * 16384;
        else if (pw < 144) src = Wa2 + (pw - 80) * 16384;
        else               src = Wv  + (pw - 144) * 16384;
        const float4* s4 = (const float4*)src;
        float4 acc = make_float4(0.f, 0.f, 0.f, 0.f);
        #pragma unroll
        for (int i = 0; i < 8; ++i) {
            float4 v = s4[i * 512 + tid];
            acc.x += v.x; acc.y += v.y; acc.z += v.z; acc.w += v.w;
        }
        ws[OFF_DUMMY + pw * 512 + tid] = acc.x + acc.y + acc.z + acc.w;
    }
}

// ---- L2: QUERY rows, TV/PQ (redundant), WKTV/WKPQ, bkt/bkq. grid 64 x 512 ----
__global__ __launch_bounds__(512) void k_prep(
    const float* __restrict__ Wk, const float* __restrict__ bk,
    const float* __restrict__ bq, const float* __restrict__ bt,
    float* __restrict__ ws)
{
    __shared__ __align__(16) float stv[512];
    __shared__ __align__(16) float spq[512];
    __shared__ float buf[8];
    int blk = blockIdx.x, tid = threadIdx.x;

    float a = 0.f;
    #pragma unroll
    for (int kc = 0; kc < 4; ++kc) a += ws[OFF_AQP + (kc * 33 + 32) * P_ + tid];
    stv[tid] = tanhf(a + bt[tid]);

    float b = 0.f;
    #pragma unroll 4
    for (int kc = 0; kc < 4; ++kc)
        for (int l = 0; l < 32; ++l) b += ws[OFF_AQP + (kc * 33 + l) * P_ + tid];
    spq[tid] = b * (1.f / 32.f) + bq[tid];

    if (blk < 32) {
        float q = bq[tid];
        #pragma unroll
        for (int kc = 0; kc < 4; ++kc) q += ws[OFF_AQP + (kc * 33 + blk) * P_ + tid];
        ws[OFF_QUERY + blk * P_ + tid] = q;
    }
    __syncthreads();

    int wv = tid >> 6, lane = tid & 63;
    int d = blk * 8 + wv;
    const float4* row = (const float4*)(Wk + d * P_);
    const float4* tv4 = (const float4*)stv;
    const float4* pq4 = (const float4*)spq;
    float4 r0 = row[lane * 2], r1 = row[lane * 2 + 1];
    float4 t0 = tv4[lane * 2], t1 = tv4[lane * 2 + 1];
    float4 q0 = pq4[lane * 2], q1 = pq4[lane * 2 + 1];
    float pa = r0.x * t0.x + r0.y * t0.y + r0.z * t0.z + r0.w * t0.w
             + r1.x * t1.x + r1.y * t1.y + r1.z * t1.z + r1.w * t1.w;
    float pb = r0.x * q0.x + r0.y * q0.y + r0.z * q0.z + r0.w * q0.w
             + r1.x * q1.x + r1.y * q1.y + r1.z * q1.z + r1.w * q1.w;
    pa = wred64(pa); pb = wred64(pb);
    if (lane == 0) { ws[OFF_WKTV + d] = pa; ws[OFF_WKPQ + d] = pb; }

    if (blk == 63) {
        float bkf = bk[tid];
        float s1 = bsum512(bkf * stv[tid], buf, tid);
        float s2 = bsum512(bkf * spq[tid], buf, tid);
        if (tid == 0) { ws[OFF_SC] = s1; ws[OFF_SC + 1] = s2; }
    }
}

// ---- L3: base scan -> row-sum in LDS -> U[t],V[t] inline. grid 1024 x 512 ----
__global__ __launch_bounds__(512) void k_scanuv(
    const float* __restrict__ base, float* __restrict__ ws)
{
    __shared__ __align__(16) float4 smem4[512];
    __shared__ __align__(16) float sfin[512];
    __shared__ float buf[8];
    int t = blockIdx.x, tid = threadIdx.x;
    const float4* bp = (const float4*)(base + (size_t)t * (L_ * D_));
    int d4 = tid & 127, lq = tid >> 7;
    float4 acc = make_float4(0.f, 0.f, 0.f, 0.f);
    #pragma unroll
    for (int i = 0; i < 8; ++i) {
        float4 v = bp[(i * 4 + lq) * 128 + d4];
        acc.x += v.x; acc.y += v.y; acc.z += v.z; acc.w += v.w;
    }
    smem4[tid] = acc;
    __syncthreads();
    if (tid < 128) {
        float4 a = smem4[tid], b2 = smem4[tid + 128];
        float4 c = smem4[tid + 256], d2 = smem4[tid + 384];
        float4 r;
        r.x = a.x + b2.x + c.x + d2.x;
        r.y = a.y + b2.y + c.y + d2.y;
        r.z = a.z + b2.z + c.z + d2.z;
        r.w = a.w + b2.w + c.w + d2.w;
        ((float4*)sfin)[tid] = r;
    }
    __syncthreads();
    float s = sfin[tid];
    float u = bsum512(s * ws[OFF_WKTV + tid], buf, tid);
    float v = bsum512(s * ws[OFF_WKPQ + tid], buf, tid);
    if (tid == 0) {
        ws[OFF_U + t] = u * (1.f / L_);
        ws[OFF_V + t] = v * (1.f / L_);
    }
}

// ---- L4: redundant task-softmax + weighted pooling PART. grid(32l,32ch) x128 ----
__global__ __launch_bounds__(128) void k_part(
    const float* __restrict__ base, float* __restrict__ out_tw,
    float* __restrict__ ws)
{
    __shared__ float sC[1024];
    __shared__ float rbuf[2];
    int l = blockIdx.x, ch = blockIdx.y, tid = threadIdx.x;
    float bkt = ws[OFF_SC], bkq = ws[OFF_SC + 1];

    float u[8], v[8], s1[8], tw1[8], tw[8];
    #pragma unroll
    for (int i = 0; i < 8; ++i) {
        int t = i * 128 + tid;
        u[i] = ws[OFF_U + t];
        v[i] = ws[OFF_V + t];
    }
    float lmax = -1e30f;
    #pragma unroll
    for (int i = 0; i < 8; ++i) { s1[i] = (u[i] + bkt) * SCALE; lmax = fmaxf(lmax, s1[i]); }
    float gmax = bmax128(lmax, rbuf, tid);
    float ls = 0.f;
    #pragma unroll
    for (int i = 0; i < 8; ++i) { s1[i] = expf(s1[i] - gmax); ls += s1[i]; }
    float gs = bsum128(ls, rbuf, tid);
    #pragma unroll
    for (int i = 0; i < 8; ++i) tw1[i] = s1[i] / gs;
    lmax = -1e30f;
    #pragma unroll
    for (int i = 0; i < 8; ++i) {
        s1[i] = ((1.f + tw1[i]) * v[i] + bkq) * SCALE;
        lmax = fmaxf(lmax, s1[i]);
    }
    gmax = bmax128(lmax, rbuf, tid);
    ls = 0.f;
    #pragma unroll
    for (int i = 0; i < 8; ++i) { s1[i] = expf(s1[i] - gmax); ls += s1[i]; }
    gs = bsum128(ls, rbuf, tid);
    float lsum = 0.f;
    #pragma unroll
    for (int i = 0; i < 8; ++i) {
        tw[i] = 0.5f * tw1[i] + 0.5f * (s1[i] / gs);
        lsum += tw[i];
    }
    float S = bsum128(lsum, rbuf, tid);
    S = fmaxf(S, 1e-6f);
    #pragma unroll
    for (int i = 0; i < 8; ++i) {
        int t = i * 128 + tid;
        float twn = tw[i] / S;
        sC[t] = twn * (1.f + tw1[i]);
        if (l == 0 && ch == 0) out_tw[t] = twn;
    }
    __syncthreads();

    float4 acc = make_float4(0.f, 0.f, 0.f, 0.f);
    for (int i = 0; i < 32; ++i) {
        int t = ch * 32 + i;
        float c = sC[t];
        float4 bv4 = ((const float4*)(base + ((size_t)t * L_ + l) * D_))[tid];
        acc.x = fmaf(c, bv4.x, acc.x);
        acc.y = fmaf(c, bv4.y, acc.y);
        acc.z = fmaf(c, bv4.z, acc.z);
        acc.w = fmaf(c, bv4.w, acc.w);
    }
    ((float4*)(ws + OFF_PART + (ch * 32 + l) * D_))[tid] = acc;
}

// ---- L5: WB reduce + split-K KV GEMM partials. grid 256 (l|sel|kc) x 512 ----
__global__ __launch_bounds__(512) void k_kv(
    const float* __restrict__ Wk, const float* __restrict__ Wv,
    float* __restrict__ ws)
{
    __shared__ float part[512];
    __shared__ float sx[128];
    int blk = blockIdx.x, tid = threadIdx.x;
    int l = blk & 31, sel = (blk >> 5) & 1, kc = blk >> 6;
    int p = tid & 127, c = tid >> 7;
    float s = 0.f;
    #pragma unroll
    for (int ch = c; ch < 32; ch += 4)
        s += ws[OFF_PART + (ch * 32 + l) * D_ + kc * 128 + p];
    part[tid] = s;
    __syncthreads();
    if (tid < 128) {
        float w = part[tid] + part[tid + 128] + part[tid + 256] + part[tid + 384];
        sx[tid] = w;
        if (sel == 0) ws[OFF_WB + l * D_ + kc * 128 + tid] = w;
    }
    __syncthreads();
    const float* W = sel ? Wv : Wk;
    float acc = 0.f;
    #pragma unroll 8
    for (int j = 0; j < 128; ++j) acc = fmaf(sx[j], W[(kc * 128 + j) * P_ + tid], acc);
    ws[OFF_AKVP + ((kc * 2 + sel) * 32 + l) * P_ + tid] = acc;
}

// ---- L6: raw logits, wave-per-(l,g). grid (32l, 8gc) x 512 ----
__global__ __launch_bounds__(512) void k_logits(
    const float* __restrict__ bk, float* __restrict__ ws)
{
    __shared__ __align__(16) float sq[512];
    int l = blockIdx.x, gc = blockIdx.y, tid = threadIdx.x;
    int wv = tid >> 6, lane = tid & 63;
    sq[tid] = ws[OFF_QUERY + l * P_ + tid];
    __syncthreads();
    const float4* sq4 = (const float4*)sq;
    const float4* bk4 = (const float4*)bk;
    float4 q0 = sq4[lane * 2], q1 = sq4[lane * 2 + 1];
    float4 A = bk4[lane * 2], B = bk4[lane * 2 + 1];
    int g = gc * 4 + wv;
    #pragma unroll
    for (int kc = 0; kc < 4; ++kc) {
        const float4* kr = (const float4*)(ws + OFF_AKVP + ((kc * 2) * 32 + g) * P_);
        float4 a = kr[lane * 2], b = kr[lane * 2 + 1];
        A.x += a.x; A.y += a.y; A.z += a.z; A.w += a.w;
        B.x += b.x; B.y += b.y; B.z += b.z; B.w += b.w;
    }
    float sdot = A.x * q0.x + A.y * q0.y + A.z * q0.z + A.w * q0.w
               + B.x * q1.x + B.y * q1.y + B.z * q1.z + B.w * q1.w;
    sdot = wred64(sdot);
    if (lane == 0) ws[OFF_LG + l * 32 + g] = sdot * SCALE;
}

// ---- L7: softmax (redundant) + EP slice + 64-deep Wo GEMM. grid (32l,8kc) ----
__global__ __launch_bounds__(512) void k_evoEP(
    const float* __restrict__ bv, const float* __restrict__ Wo,
    float* __restrict__ out_fa, float* __restrict__ ws)
{
    __shared__ float slg[32];
    __shared__ float sfa[32];
    __shared__ float pe[8][64];
    __shared__ float sx[64];
    int l = blockIdx.x, kc = blockIdx.y, tid = threadIdx.x;
    if (tid < 32) slg[tid] = ws[OFF_LG + l * 32 + tid];
    __syncthreads();
    if (tid < 32) {
        float mx = -1e30f;
        for (int i = 0; i < 32; ++i) mx = fmaxf(mx, slg[i]);
        float S = 0.f;
        for (int i = 0; i < 32; ++i) S += expf(slg[i] - mx);
        float f = expf(slg[tid] - mx) / S;
        sfa[tid] = f;
        if (kc == 0) out_fa[l * 32 + tid] = f;
    }
    __syncthreads();

    int p = tid & 63, jg = tid >> 6;
    float bvp = bv[kc * 64 + p];
    float acc = 0.f;
    #pragma unroll
    for (int jj = 0; jj < 4; ++jj) {
        int j = jg * 4 + jj;
        float vs = ws[OFF_AKVP + (1 * 32 + j) * P_ + kc * 64 + p]
                 + ws[OFF_AKVP + (3 * 32 + j) * P_ + kc * 64 + p]
                 + ws[OFF_AKVP + (5 * 32 + j) * P_ + kc * 64 + p]
                 + ws[OFF_AKVP + (7 * 32 + j) * P_ + kc * 64 + p];
        acc = fmaf(sfa[j], vs + bvp, acc);
    }
    pe[jg][p] = acc;
    __syncthreads();
    if (tid < 64) {
        float s = 0.f;
        #pragma unroll
        for (int i = 0; i < 8; ++i) s += pe[i][tid];
        sx[tid] = s;
    }
    __syncthreads();

    float a2 = 0.f;
    #pragma unroll 8
    for (int j = 0; j < 64; ++j) a2 = fmaf(sx[j], Wo[(kc * 64 + j) * D_ + tid], a2);
    ws[OFF_AEVOP + (kc * 32 + l) * D_ + tid] = a2;
}

// ---- L8: LN_in -> EVOLVED (materialized once). grid 32 x 512 ----
__global__ __launch_bounds__(512) void k_lnin(
    const float* __restrict__ bo, const float* __restrict__ g_in,
    const float* __restrict__ b_in, float* __restrict__ ws)
{
    __shared__ float buf[8];
    int l = blockIdx.x, tid = threadIdx.x;
    float x = ws[OFF_WB + l * D_ + tid] + bo[tid];
    #pragma unroll
    for (int k2 = 0; k2 < 8; ++k2) x += ws[OFF_AEVOP + (k2 * 32 + l) * D_ + tid];
    float mean = bsum512(x, buf, tid) * (1.f / D_);
    float dx = x - mean;
    float var = bsum512(dx * dx, buf, tid) * (1.f / D_);
    ws[OFF_EVOLVED + l * D_ + tid] = dx * rsqrtf(var + EPS_) * g_in[tid] + b_in[tid];
}

// ---- L9: MLP1, 4-l-batched split-K. grid 128 (lg|hc|kc) x 512 ----
__global__ __launch_bounds__(512) void k_mlp1(
    const float* __restrict__ Wa1, float* __restrict__ ws)
{
    __shared__ float sevo[4][512];
    int blk = blockIdx.x, tid = threadIdx.x;
    int lg = blk & 7, hc = (blk >> 3) & 3, kc = blk >> 5;   // kc 0..3
    #pragma unroll
    for (int r = 0; r < 4; ++r)
        sevo[r][tid] = ws[OFF_EVOLVED + (lg * 4 + r) * D_ + tid];
    __syncthreads();
    int h = hc * 512 + tid;
    float a0 = 0.f, a1 = 0.f, a2 = 0.f, a3 = 0.f;
    #pragma unroll 8
    for (int j = 0; j < 128; ++j) {
        float w = Wa1[(kc * 128 + j) * H_ + h];
        a0 = fmaf(sevo[0][kc * 128 + j], w, a0);
        a1 = fmaf(sevo[1][kc * 128 + j], w, a1);
        a2 = fmaf(sevo[2][kc * 128 + j], w, a2);
        a3 = fmaf(sevo[3][kc * 128 + j], w, a3);
    }
    ws[OFF_AH1P + (kc * 32 + lg * 4 + 0) * H_ + h] = a0;
    ws[OFF_AH1P + (kc * 32 + lg * 4 + 1) * H_ + h] = a1;
    ws[OFF_AH1P + (kc * 32 + lg * 4 + 2) * H_ + h] = a2;
    ws[OFF_AH1P + (kc * 32 + lg * 4 + 3) * H_ + h] = a3;
}

// ---- L10: MLP2, 4-l-batched split-K (relu+bias inline). grid 128 (lg|kc) ----
__global__ __launch_bounds__(512) void k_mlp2(
    const float* __restrict__ Wa2, const float* __restrict__ ba1,
    float* __restrict__ ws)
{
    __shared__ float sh[4][128];
    int blk = blockIdx.x, tid = threadIdx.x;
    int lg = blk & 7, kc = blk >> 3;   // kc 0..15
    {
        int hh = tid & 127, r = tid >> 7;
        int h = kc * 128 + hh;
        float a = ba1[h];
        #pragma unroll
        for (int k4 = 0; k4 < 4; ++k4)
            a += ws[OFF_AH1P + (k4 * 32 + lg * 4 + r) * H_ + h];
        sh[r][hh] = fmaxf(a, 0.f);
    }
    __syncthreads();
    float a0 = 0.f, a1 = 0.f, a2 = 0.f, a3 = 0.f;
    #pragma unroll 8
    for (int j = 0; j < 128; ++j) {
        float w = Wa2[(kc * 128 + j) * D_ + tid];
        a0 = fmaf(sh[0][j], w, a0);
        a1 = fmaf(sh[1][j], w, a1);
        a2 = fmaf(sh[2][j], w, a2);
        a3 = fmaf(sh[3][j], w, a3);
    }
    ws[OFF_AOUTP + (kc * 32 + lg * 4 + 0) * D_ + tid] = a0;
    ws[OFF_AOUTP + (kc * 32 + lg * 4 + 1) * D_ + tid] = a1;
    ws[OFF_AOUTP + (kc * 32 + lg * 4 + 2) * D_ + tid] = a2;
    ws[OFF_AOUTP + (kc * 32 + lg * 4 + 3) * D_ + tid] = a3;
}

// ---- L11: LN_out + aligned + broadcast. grid (32l, 32tc) x 512 ----
__global__ __launch_bounds__(512) void k_lnbcast(
    const float* __restrict__ ba2, const float* __restrict__ g_out,
    const float* __restrict__ b_out, float* __restrict__ out,
    float* __restrict__ ws)
{
    __shared__ float buf[8];
    __shared__ __align__(16) float sal[512];
    int l = blockIdx.x, tc = blockIdx.y, tid = threadIdx.x;
    float x2 = ws[OFF_EVOLVED + l * D_ + tid] + ba2[tid];
    #pragma unroll
    for (int kc = 0; kc < 16; ++kc) x2 += ws[OFF_AOUTP + (kc * 32 + l) * D_ + tid];
    float mean2 = bsum512(x2, buf, tid) * (1.f / D_);
    float dx2 = x2 - mean2;
    float var2 = bsum512(dx2 * dx2, buf, tid) * (1.f / D_);
    float a = dx2 * rsqrtf(var2 + EPS_) * g_out[tid] + b_out[tid];
    if (tc == 0) out[OFFO_AL + l * D_ + tid] = a;
    sal[tid] = a;
    __syncthreads();
    float4 v = ((const float4*)sal)[tid & 127];
    int row = tid >> 7;
    #pragma unroll
    for (int pass = 0; pass < 8; ++pass) {
        int t = tc * 32 + pass * 4 + row;
        ((float4*)(out + OFFO_AP + (size_t)t * (L_ * D_) + l * D_))[tid & 127] = v;
    }
}

extern "C" void kernel_launch(void* const* d_in, const int* in_sizes, int n_in,
                              void* d_out, int out_size, void* d_ws, size_t ws_size,
                              hipStream_t stream) {
    const float* base = (const float*)d_in[0];
    const float* np   = (const float*)d_in[1];
    const float* te   = (const float*)d_in[2];
    const float* Wt   = (const float*)d_in[3];
    const float* bt   = (const float*)d_in[4];
    const float* Wq   = (const float*)d_in[5];
    const float* bq   = (const float*)d_in[6];
    const float* Wk   = (const float*)d_in[7];
    const float* bk   = (const float*)d_in[8];
    const float* Wv   = (const float*)d_in[9];
    const float* bv   = (const float*)d_in[10];
    const float* Wo   = (const float*)d_in[11];
    const float* bo   = (const float*)d_in[12];
    const float* Wa1  = (const float*)d_in[13];
    const float* ba1  = (const float*)d_in[14];
    const float* Wa2  = (const float*)d_in[15];
    const float* ba2  = (const float*)d_in[16];
    const float* g_in = (const float*)d_in[17];
    const float* b_in = (const float*)d_in[18];
    const float* g_out= (const float*)d_in[19];
    const float* b_out= (const float*)d_in[20];
    float* out = (float*)d_out;
    float* ws = (float*)d_ws;

    hipLaunchKernelGGL(k_aq,      dim3(292),    dim3(512), 0, stream,
                       np, te, Wq, Wt, Wv, Wo, Wa1, Wa2, ws);
    hipLaunchKernelGGL(k_prep,    dim3(64),     dim3(512), 0, stream, Wk, bk, bq, bt, ws);
    hipLaunchKernelGGL(k_scanuv,  dim3(1024),   dim3(512), 0, stream, base, ws);
    hipLaunchKernelGGL(k_part,    dim3(32, 32), dim3(128), 0, stream, base, out + OFFO_TW, ws);
    hipLaunchKernelGGL(k_kv,      dim3(256),    dim3(512), 0, stream, Wk, Wv, ws);
    hipLaunchKernelGGL(k_logits,  dim3(32, 8),  dim3(512), 0, stream, bk, ws);
    hipLaunchKernelGGL(k_evoEP,   dim3(32, 8),  dim3(512), 0, stream, bv, Wo, out + OFFO_FA, ws);
    hipLaunchKernelGGL(k_lnin,    dim3(32),     dim3(512), 0, stream, bo, g_in, b_in, ws);
    hipLaunchKernelGGL(k_mlp1,    dim3(128),    dim3(512), 0, stream, Wa1, ws);
    hipLaunchKernelGGL(k_mlp2,    dim3(128),    dim3(512), 0, stream, Wa2, ba1, ws);
    hipLaunchKernelGGL(k_lnbcast, dim3(32, 32), dim3(512), 0, stream,
                       ba2, g_out, b_out, out, ws);
}

// Round 8
// 231.747 us; speedup vs baseline: 2.8428x; 1.0182x over previous
//
#include <hip/hip_runtime.h>

// RainbowEvolution T=1024 L=32 D=512 P=512 H=2048. fp32 in / fp32 out.
// R13: fixes R11/R12 k_logits RACE (g=gc*4+wv spanned [0,35]: cross-l writes;
// absmax 0.0039->0.0156 was the symptom) by folding logits into k_evoEP
// (computed redundantly per block, coalesced p=e*16+li). Also:
//  - k_part: 256x512 blocks (was 1024x128) -> redundant softmax 1 round not 4;
//    PART layout [8ch][32][512].
//  - k_kv 4-l-batched (64 blocks): weight L2 traffic 64MB -> 16MB.
// 10 launches. Split-K partials, no atomics, no zero pass. Scratch in d_ws.

static constexpr int T_ = 1024, L_ = 32, D_ = 512, P_ = 512, H_ = 2048;
static constexpr float SCALE = 0.04419417382415922f; // 1/sqrt(512)
static constexpr float EPS_ = 1e-5f;

// out layout (fp32 offsets)
static constexpr int OFFO_AL = 0;
static constexpr int OFFO_AP = 16384;
static constexpr int OFFO_TW = 16384 + 16777216;   // 16793600
static constexpr int OFFO_FA = OFFO_TW + 1024;     // 16794624

// scratch (fp32 offsets into ws = (float*)d_ws)
static constexpr int OFF_AQP     = 0;        // [4kc][33][512]
static constexpr int OFF_QUERY   = 67584;    // [32][512]
static constexpr int OFF_WKTV    = 83968;    // [512]
static constexpr int OFF_WKPQ    = 84480;    // [512]
static constexpr int OFF_SC      = 84992;    // [64] scalars: bkt, bkq
static constexpr int OFF_U       = 85056;    // [1024]
static constexpr int OFF_V       = 86080;    // [1024]
static constexpr int OFF_PART    = 87104;    // [8ch][32l][512]
static constexpr int OFF_WB      = 611392;   // [32][512]
static constexpr int OFF_AKVP    = 627776;   // [4kc][2sel][32][512]
static constexpr int OFF_AEVOP   = 759872;   // [8kc][32][512]
static constexpr int OFF_EVOLVED = 890944;   // [32][512]
static constexpr int OFF_AH1P    = 907328;   // [4kc][32][2048]
static constexpr int OFF_AOUTP   = 1169472;  // [16kc][32][512]
static constexpr int OFF_DUMMY   = 1431616;  // [160*512] prewarm sink

// ---- reductions ----
__device__ __forceinline__ float wred64(float v) {
    #pragma unroll
    for (int off = 32; off > 0; off >>= 1) v += __shfl_down(v, off, 64);
    return v;
}
__device__ __forceinline__ float wmax64(float v) {
    #pragma unroll
    for (int off = 32; off > 0; off >>= 1) v = fmaxf(v, __shfl_down(v, off, 64));
    return v;
}
__device__ __forceinline__ float bsum512(float v, float* buf, int tid) {
    v = wred64(v);
    __syncthreads();
    if ((tid & 63) == 0) buf[tid >> 6] = v;
    __syncthreads();
    float s = 0.f;
    #pragma unroll
    for (int i = 0; i < 8; ++i) s += buf[i];
    return s;
}
__device__ __forceinline__ float bmax512(float v, float* buf, int tid) {
    v = wmax64(v);
    __syncthreads();
    if ((tid & 63) == 0) buf[tid >> 6] = v;
    __syncthreads();
    float m = buf[0];
    #pragma unroll
    for (int i = 1; i < 8; ++i) m = fmaxf(m, buf[i]);
    return m;
}

// ---- L1: AQ partials (0..131) + prewarm Wo/Wa1/Wa2/Wv (132..291) ----
__global__ __launch_bounds__(512) void k_aq(
    const float* __restrict__ np_, const float* __restrict__ te,
    const float* __restrict__ Wq, const float* __restrict__ Wt,
    const float* __restrict__ Wv, const float* __restrict__ Wo,
    const float* __restrict__ Wa1, const float* __restrict__ Wa2,
    float* __restrict__ ws)
{
    __shared__ float sx[128];
    int blk = blockIdx.x, tid = threadIdx.x;
    if (blk < 132) {
        int b = blk % 33, kc = blk / 33;
        const float* x = (b < 32) ? (np_ + b * D_) : te;
        const float* W = (b < 32) ? Wq : Wt;
        if (tid < 128) sx[tid] = x[kc * 128 + tid];
        __syncthreads();
        float acc = 0.f;
        #pragma unroll 8
        for (int j = 0; j < 128; ++j) acc = fmaf(sx[j], W[(kc * 128 + j) * P_ + tid], acc);
        ws[OFF_AQP + (kc * 33 + b) * P_ + tid] = acc;
    } else {
        int pw = blk - 132;     // Wo 0-15, Wa1 16-79, Wa2 80-143, Wv 144-159
        const float* src;
        if (pw < 16)       src = Wo  + pw * 16384;
        else if (pw < 80)  src = Wa1 + (pw - 16) * 16384;
        else if (pw < 144) src = Wa2 + (pw - 80) * 16384;
        else               src = Wv  + (pw - 144) * 16384;
        const float4* s4 = (const float4*)src;
        float4 acc = make_float4(0.f, 0.f, 0.f, 0.f);
        #pragma unroll
        for (int i = 0; i < 8; ++i) {
            float4 v = s4[i * 512 + tid];
            acc.x += v.x; acc.y += v.y; acc.z += v.z; acc.w += v.w;
        }
        ws[OFF_DUMMY + pw * 512 + tid] = acc.x + acc.y + acc.z + acc.w;
    }
}

// ---- L2: QUERY rows, TV/PQ (redundant), WKTV/WKPQ, bkt/bkq. grid 64 x 512 ----
__global__ __launch_bounds__(512) void k_prep(
    const float* __restrict__ Wk, const float* __restrict__ bk,
    const float* __restrict__ bq, const float* __restrict__ bt,
    float* __restrict__ ws)
{
    __shared__ __align__(16) float stv[512];
    __shared__ __align__(16) float spq[512];
    __shared__ float buf[8];
    int blk = blockIdx.x, tid = threadIdx.x;

    float a = 0.f;
    #pragma unroll
    for (int kc = 0; kc < 4; ++kc) a += ws[OFF_AQP + (kc * 33 + 32) * P_ + tid];
    stv[tid] = tanhf(a + bt[tid]);

    float b = 0.f;
    #pragma unroll 4
    for (int kc = 0; kc < 4; ++kc)
        for (int l = 0; l < 32; ++l) b += ws[OFF_AQP + (kc * 33 + l) * P_ + tid];
    spq[tid] = b * (1.f / 32.f) + bq[tid];

    if (blk < 32) {
        float q = bq[tid];
        #pragma unroll
        for (int kc = 0; kc < 4; ++kc) q += ws[OFF_AQP + (kc * 33 + blk) * P_ + tid];
        ws[OFF_QUERY + blk * P_ + tid] = q;
    }
    __syncthreads();

    int wv = tid >> 6, lane = tid & 63;
    int d = blk * 8 + wv;
    const float4* row = (const float4*)(Wk + d * P_);
    const float4* tv4 = (const float4*)stv;
    const float4* pq4 = (const float4*)spq;
    float4 r0 = row[lane * 2], r1 = row[lane * 2 + 1];
    float4 t0 = tv4[lane * 2], t1 = tv4[lane * 2 + 1];
    float4 q0 = pq4[lane * 2], q1 = pq4[lane * 2 + 1];
    float pa = r0.x * t0.x + r0.y * t0.y + r0.z * t0.z + r0.w * t0.w
             + r1.x * t1.x + r1.y * t1.y + r1.z * t1.z + r1.w * t1.w;
    float pb = r0.x * q0.x + r0.y * q0.y + r0.z * q0.z + r0.w * q0.w
             + r1.x * q1.x + r1.y * q1.y + r1.z * q1.z + r1.w * q1.w;
    pa = wred64(pa); pb = wred64(pb);
    if (lane == 0) { ws[OFF_WKTV + d] = pa; ws[OFF_WKPQ + d] = pb; }

    if (blk == 63) {
        float bkf = bk[tid];
        float s1 = bsum512(bkf * stv[tid], buf, tid);
        float s2 = bsum512(bkf * spq[tid], buf, tid);
        if (tid == 0) { ws[OFF_SC] = s1; ws[OFF_SC + 1] = s2; }
    }
}

// ---- L3: base scan -> row-sum in LDS -> U[t],V[t] inline. grid 1024 x 512 ----
__global__ __launch_bounds__(512) void k_scanuv(
    const float* __restrict__ base, float* __restrict__ ws)
{
    __shared__ __align__(16) float4 smem4[512];
    __shared__ __align__(16) float sfin[512];
    __shared__ float buf[8];
    int t = blockIdx.x, tid = threadIdx.x;
    const float4* bp = (const float4*)(base + (size_t)t * (L_ * D_));
    int d4 = tid & 127, lq = tid >> 7;
    float4 acc = make_float4(0.f, 0.f, 0.f, 0.f);
    #pragma unroll
    for (int i = 0; i < 8; ++i) {
        float4 v = bp[(i * 4 + lq) * 128 + d4];
        acc.x += v.x; acc.y += v.y; acc.z += v.z; acc.w += v.w;
    }
    smem4[tid] = acc;
    __syncthreads();
    if (tid < 128) {
        float4 a = smem4[tid], b2 = smem4[tid + 128];
        float4 c = smem4[tid + 256], d2 = smem4[tid + 384];
        float4 r;
        r.x = a.x + b2.x + c.x + d2.x;
        r.y = a.y + b2.y + c.y + d2.y;
        r.z = a.z + b2.z + c.z + d2.z;
        r.w = a.w + b2.w + c.w + d2.w;
        ((float4*)sfin)[tid] = r;
    }
    __syncthreads();
    float s = sfin[tid];
    float u = bsum512(s * ws[OFF_WKTV + tid], buf, tid);
    float v = bsum512(s * ws[OFF_WKPQ + tid], buf, tid);
    if (tid == 0) {
        ws[OFF_U + t] = u * (1.f / L_);
        ws[OFF_V + t] = v * (1.f / L_);
    }
}

// ---- L4: redundant task-softmax + weighted pooling. grid (32l, 8chg) x 512 ----
__global__ __launch_bounds__(512) void k_part(
    const float* __restrict__ base, float* __restrict__ out_tw,
    float* __restrict__ ws)
{
    __shared__ float sC[1024];
    __shared__ float buf[8];
    __shared__ __align__(16) float4 s4[512];
    int l = blockIdx.x, chg = blockIdx.y, tid = threadIdx.x;
    float bkt = ws[OFF_SC], bkq = ws[OFF_SC + 1];

    float u[2], v[2], s1[2], tw1[2], tw[2];
    #pragma unroll
    for (int i = 0; i < 2; ++i) {
        int t = i * 512 + tid;
        u[i] = ws[OFF_U + t];
        v[i] = ws[OFF_V + t];
    }
    float lmax = -1e30f;
    #pragma unroll
    for (int i = 0; i < 2; ++i) { s1[i] = (u[i] + bkt) * SCALE; lmax = fmaxf(lmax, s1[i]); }
    float gmax = bmax512(lmax, buf, tid);
    float ls = 0.f;
    #pragma unroll
    for (int i = 0; i < 2; ++i) { s1[i] = expf(s1[i] - gmax); ls += s1[i]; }
    float gs = bsum512(ls, buf, tid);
    #pragma unroll
    for (int i = 0; i < 2; ++i) tw1[i] = s1[i] / gs;
    lmax = -1e30f;
    #pragma unroll
    for (int i = 0; i < 2; ++i) {
        s1[i] = ((1.f + tw1[i]) * v[i] + bkq) * SCALE;
        lmax = fmaxf(lmax, s1[i]);
    }
    gmax = bmax512(lmax, buf, tid);
    ls = 0.f;
    #pragma unroll
    for (int i = 0; i < 2; ++i) { s1[i] = expf(s1[i] - gmax); ls += s1[i]; }
    gs = bsum512(ls, buf, tid);
    float lsum = 0.f;
    #pragma unroll
    for (int i = 0; i < 2; ++i) {
        tw[i] = 0.5f * tw1[i] + 0.5f * (s1[i] / gs);
        lsum += tw[i];
    }
    float S = bsum512(lsum, buf, tid);
    S = fmaxf(S, 1e-6f);
    #pragma unroll
    for (int i = 0; i < 2; ++i) {
        int t = i * 512 + tid;
        float twn = tw[i] / S;
        sC[t] = twn * (1.f + tw1[i]);
        if (l == 0 && chg == 0) out_tw[t] = twn;
    }
    __syncthreads();

    // pooling: 128 t per chg, 4 t-quarters x 32
    int d4 = tid & 127, tq = tid >> 7;
    float4 acc = make_float4(0.f, 0.f, 0.f, 0.f);
    for (int i = 0; i < 32; ++i) {
        int t = chg * 128 + tq * 32 + i;
        float c = sC[t];
        float4 bv4 = ((const float4*)(base + ((size_t)t * L_ + l) * D_))[d4];
        acc.x = fmaf(c, bv4.x, acc.x);
        acc.y = fmaf(c, bv4.y, acc.y);
        acc.z = fmaf(c, bv4.z, acc.z);
        acc.w = fmaf(c, bv4.w, acc.w);
    }
    s4[tid] = acc;
    __syncthreads();
    if (tid < 128) {
        float4 a = s4[tid], b2 = s4[tid + 128], c2 = s4[tid + 256], d2 = s4[tid + 384];
        float4 r;
        r.x = a.x + b2.x + c2.x + d2.x;
        r.y = a.y + b2.y + c2.y + d2.y;
        r.z = a.z + b2.z + c2.z + d2.z;
        r.w = a.w + b2.w + c2.w + d2.w;
        ((float4*)(ws + OFF_PART + (chg * 32 + l) * D_))[tid] = r;
    }
}

// ---- L5: WB reduce + split-K KV GEMM, 4-l-batched. grid (8lg,2sel,4kc) x 512 ----
__global__ __launch_bounds__(512) void k_kv(
    const float* __restrict__ Wk, const float* __restrict__ Wv,
    float* __restrict__ ws)
{
    __shared__ float sx[4][128];
    int lg = blockIdx.x, sel = blockIdx.y, kc = blockIdx.z, tid = threadIdx.x;
    int r = tid >> 7, p = tid & 127;
    int l = lg * 4 + r;
    float s = 0.f;
    #pragma unroll
    for (int ch = 0; ch < 8; ++ch)
        s += ws[OFF_PART + (ch * 32 + l) * D_ + kc * 128 + p];
    sx[r][p] = s;
    if (sel == 0) ws[OFF_WB + l * D_ + kc * 128 + p] = s;
    __syncthreads();
    const float* W = sel ? Wv : Wk;
    float a0 = 0.f, a1 = 0.f, a2 = 0.f, a3 = 0.f;
    #pragma unroll 8
    for (int j = 0; j < 128; ++j) {
        float w = W[(kc * 128 + j) * P_ + tid];
        a0 = fmaf(sx[0][j], w, a0);
        a1 = fmaf(sx[1][j], w, a1);
        a2 = fmaf(sx[2][j], w, a2);
        a3 = fmaf(sx[3][j], w, a3);
    }
    int bi = (kc * 2 + sel) * 32 + lg * 4;
    ws[OFF_AKVP + (bi + 0) * P_ + tid] = a0;
    ws[OFF_AKVP + (bi + 1) * P_ + tid] = a1;
    ws[OFF_AKVP + (bi + 2) * P_ + tid] = a2;
    ws[OFF_AKVP + (bi + 3) * P_ + tid] = a3;
}

// ---- L6: inline logits (redundant per block) + softmax + EP slice +
//          64-deep Wo GEMM. grid (32l, 8kc) x 512 ----
__global__ __launch_bounds__(512) void k_evoEP(
    const float* __restrict__ bk, const float* __restrict__ bv,
    const float* __restrict__ Wo, float* __restrict__ out_fa,
    float* __restrict__ ws)
{
    __shared__ __align__(16) float sq[512];
    __shared__ float slg[32];
    __shared__ float sfa[32];
    __shared__ float pe[8][64];
    __shared__ float sx[64];
    int l = blockIdx.x, kc = blockIdx.y, tid = threadIdx.x;
    sq[tid] = ws[OFF_QUERY + l * P_ + tid];
    __syncthreads();

    // logits: 16 threads per g, coalesced p = e*16 + li
    int g = tid >> 4, li = tid & 15;
    float sd = 0.f;
    #pragma unroll 4
    for (int e = 0; e < 32; ++e) {
        int p = e * 16 + li;
        float k = bk[p]
                + ws[OFF_AKVP + (g) * P_ + p]
                + ws[OFF_AKVP + (64 + g) * P_ + p]
                + ws[OFF_AKVP + (128 + g) * P_ + p]
                + ws[OFF_AKVP + (192 + g) * P_ + p];
        sd = fmaf(k, sq[p], sd);
    }
    #pragma unroll
    for (int off = 8; off > 0; off >>= 1) sd += __shfl_down(sd, off, 16);
    if (li == 0) slg[g] = sd * SCALE;
    __syncthreads();

    if (tid < 32) {
        float mx = -1e30f;
        for (int i = 0; i < 32; ++i) mx = fmaxf(mx, slg[i]);
        float S = 0.f;
        for (int i = 0; i < 32; ++i) S += expf(slg[i] - mx);
        float f = expf(slg[tid] - mx) / S;
        sfa[tid] = f;
        if (kc == 0) out_fa[l * 32 + tid] = f;
    }
    __syncthreads();

    int p = tid & 63, jg = tid >> 6;
    float bvp = bv[kc * 64 + p];
    float acc = 0.f;
    #pragma unroll
    for (int jj = 0; jj < 4; ++jj) {
        int j = jg * 4 + jj;
        float vs = ws[OFF_AKVP + (32 + j) * P_ + kc * 64 + p]
                 + ws[OFF_AKVP + (96 + j) * P_ + kc * 64 + p]
                 + ws[OFF_AKVP + (160 + j) * P_ + kc * 64 + p]
                 + ws[OFF_AKVP + (224 + j) * P_ + kc * 64 + p];
        acc = fmaf(sfa[j], vs + bvp, acc);
    }
    pe[jg][p] = acc;
    __syncthreads();
    if (tid < 64) {
        float s = 0.f;
        #pragma unroll
        for (int i = 0; i < 8; ++i) s += pe[i][tid];
        sx[tid] = s;
    }
    __syncthreads();

    float a2 = 0.f;
    #pragma unroll 8
    for (int j = 0; j < 64; ++j) a2 = fmaf(sx[j], Wo[(kc * 64 + j) * D_ + tid], a2);
    ws[OFF_AEVOP + (kc * 32 + l) * D_ + tid] = a2;
}

// ---- L7: LN_in -> EVOLVED. grid 32 x 512 ----
__global__ __launch_bounds__(512) void k_lnin(
    const float* __restrict__ bo, const float* __restrict__ g_in,
    const float* __restrict__ b_in, float* __restrict__ ws)
{
    __shared__ float buf[8];
    int l = blockIdx.x, tid = threadIdx.x;
    float x = ws[OFF_WB + l * D_ + tid] + bo[tid];
    #pragma unroll
    for (int k2 = 0; k2 < 8; ++k2) x += ws[OFF_AEVOP + (k2 * 32 + l) * D_ + tid];
    float mean = bsum512(x, buf, tid) * (1.f / D_);
    float dx = x - mean;
    float var = bsum512(dx * dx, buf, tid) * (1.f / D_);
    ws[OFF_EVOLVED + l * D_ + tid] = dx * rsqrtf(var + EPS_) * g_in[tid] + b_in[tid];
}

// ---- L8: MLP1, 4-l-batched split-K. grid 128 (lg|hc|kc) x 512 ----
__global__ __launch_bounds__(512) void k_mlp1(
    const float* __restrict__ Wa1, float* __restrict__ ws)
{
    __shared__ float sevo[4][512];
    int blk = blockIdx.x, tid = threadIdx.x;
    int lg = blk & 7, hc = (blk >> 3) & 3, kc = blk >> 5;   // kc 0..3
    #pragma unroll
    for (int r = 0; r < 4; ++r)
        sevo[r][tid] = ws[OFF_EVOLVED + (lg * 4 + r) * D_ + tid];
    __syncthreads();
    int h = hc * 512 + tid;
    float a0 = 0.f, a1 = 0.f, a2 = 0.f, a3 = 0.f;
    #pragma unroll 8
    for (int j = 0; j < 128; ++j) {
        float w = Wa1[(kc * 128 + j) * H_ + h];
        a0 = fmaf(sevo[0][kc * 128 + j], w, a0);
        a1 = fmaf(sevo[1][kc * 128 + j], w, a1);
        a2 = fmaf(sevo[2][kc * 128 + j], w, a2);
        a3 = fmaf(sevo[3][kc * 128 + j], w, a3);
    }
    ws[OFF_AH1P + (kc * 32 + lg * 4 + 0) * H_ + h] = a0;
    ws[OFF_AH1P + (kc * 32 + lg * 4 + 1) * H_ + h] = a1;
    ws[OFF_AH1P + (kc * 32 + lg * 4 + 2) * H_ + h] = a2;
    ws[OFF_AH1P + (kc * 32 + lg * 4 + 3) * H_ + h] = a3;
}

// ---- L9: MLP2, 4-l-batched split-K (relu+bias inline). grid 128 (lg|kc) ----
__global__ __launch_bounds__(512) void k_mlp2(
    const float* __restrict__ Wa2, const float* __restrict__ ba1,
    float* __restrict__ ws)
{
    __shared__ float sh[4][128];
    int blk = blockIdx.x, tid = threadIdx.x;
    int lg = blk & 7, kc = blk >> 3;   // kc 0..15
    {
        int hh = tid & 127, r = tid >> 7;
        int h = kc * 128 + hh;
        float a = ba1[h];
        #pragma unroll
        for (int k4 = 0; k4 < 4; ++k4)
            a += ws[OFF_AH1P + (k4 * 32 + lg * 4 + r) * H_ + h];
        sh[r][hh] = fmaxf(a, 0.f);
    }
    __syncthreads();
    float a0 = 0.f, a1 = 0.f, a2 = 0.f, a3 = 0.f;
    #pragma unroll 8
    for (int j = 0; j < 128; ++j) {
        float w = Wa2[(kc * 128 + j) * D_ + tid];
        a0 = fmaf(sh[0][j], w, a0);
        a1 = fmaf(sh[1][j], w, a1);
        a2 = fmaf(sh[2][j], w, a2);
        a3 = fmaf(sh[3][j], w, a3);
    }
    ws[OFF_AOUTP + (kc * 32 + lg * 4 + 0) * D_ + tid] = a0;
    ws[OFF_AOUTP + (kc * 32 + lg * 4 + 1) * D_ + tid] = a1;
    ws[OFF_AOUTP + (kc * 32 + lg * 4 + 2) * D_ + tid] = a2;
    ws[OFF_AOUTP + (kc * 32 + lg * 4 + 3) * D_ + tid] = a3;
}

// ---- L10: LN_out + aligned + broadcast. grid (32l, 32tc) x 512 ----
__global__ __launch_bounds__(512) void k_lnbcast(
    const float* __restrict__ ba2, const float* __restrict__ g_out,
    const float* __restrict__ b_out, float* __restrict__ out,
    float* __restrict__ ws)
{
    __shared__ float buf[8];
    __shared__ __align__(16) float sal[512];
    int l = blockIdx.x, tc = blockIdx.y, tid = threadIdx.x;
    float x2 = ws[OFF_EVOLVED + l * D_ + tid] + ba2[tid];
    #pragma unroll
    for (int kc = 0; kc < 16; ++kc) x2 += ws[OFF_AOUTP + (kc * 32 + l) * D_ + tid];
    float mean2 = bsum512(x2, buf, tid) * (1.f / D_);
    float dx2 = x2 - mean2;
    float var2 = bsum512(dx2 * dx2, buf, tid) * (1.f / D_);
    float a = dx2 * rsqrtf(var2 + EPS_) * g_out[tid] + b_out[tid];
    if (tc == 0) out[OFFO_AL + l * D_ + tid] = a;
    sal[tid] = a;
    __syncthreads();
    float4 v = ((const float4*)sal)[tid & 127];
    int row = tid >> 7;
    #pragma unroll
    for (int pass = 0; pass < 8; ++pass) {
        int t = tc * 32 + pass * 4 + row;
        ((float4*)(out + OFFO_AP + (size_t)t * (L_ * D_) + l * D_))[tid & 127] = v;
    }
}

extern "C" void kernel_launch(void* const* d_in, const int* in_sizes, int n_in,
                              void* d_out, int out_size, void* d_ws, size_t ws_size,
                              hipStream_t stream) {
    const float* base = (const float*)d_in[0];
    const float* np   = (const float*)d_in[1];
    const float* te   = (const float*)d_in[2];
    const float* Wt   = (const float*)d_in[3];
    const float* bt   = (const float*)d_in[4];
    const float* Wq   = (const float*)d_in[5];
    const float* bq   = (const float*)d_in[6];
    const float* Wk   = (const float*)d_in[7];
    const float* bk   = (const float*)d_in[8];
    const float* Wv   = (const float*)d_in[9];
    const float* bv   = (const float*)d_in[10];
    const float* Wo   = (const float*)d_in[11];
    const float* bo   = (const float*)d_in[12];
    const float* Wa1  = (const float*)d_in[13];
    const float* ba1  = (const float*)d_in[14];
    const float* Wa2  = (const float*)d_in[15];
    const float* ba2  = (const float*)d_in[16];
    const float* g_in = (const float*)d_in[17];
    const float* b_in = (const float*)d_in[18];
    const float* g_out= (const float*)d_in[19];
    const float* b_out= (const float*)d_in[20];
    float* out = (float*)d_out;
    float* ws = (float*)d_ws;

    hipLaunchKernelGGL(k_aq,      dim3(292),      dim3(512), 0, stream,
                       np, te, Wq, Wt, Wv, Wo, Wa1, Wa2, ws);
    hipLaunchKernelGGL(k_prep,    dim3(64),       dim3(512), 0, stream, Wk, bk, bq, bt, ws);
    hipLaunchKernelGGL(k_scanuv,  dim3(1024),     dim3(512), 0, stream, base, ws);
    hipLaunchKernelGGL(k_part,    dim3(32, 8),    dim3(512), 0, stream, base, out + OFFO_TW, ws);
    hipLaunchKernelGGL(k_kv,      dim3(8, 2, 4),  dim3(512), 0, stream, Wk, Wv, ws);
    hipLaunchKernelGGL(k_evoEP,   dim3(32, 8),    dim3(512), 0, stream, bk, bv, Wo, out + OFFO_FA, ws);
    hipLaunchKernelGGL(k_lnin,    dim3(32),       dim3(512), 0, stream, bo, g_in, b_in, ws);
    hipLaunchKernelGGL(k_mlp1,    dim3(128),      dim3(512), 0, stream, Wa1, ws);
    hipLaunchKernelGGL(k_mlp2,    dim3(128),      dim3(512), 0, stream, Wa2, ba1, ws);
    hipLaunchKernelGGL(k_lnbcast, dim3(32, 32),   dim3(512), 0, stream,
                       ba2, g_out, b_out, out, ws);
}